// Round 4
// baseline (1656.169 us; speedup 1.0000x reference)
//
#include <hip/hip_runtime.h>
#include <hip/hip_bf16.h>

// MusicGNN — 3-layer GCN encoder + MLP link predictor.
// N=100000, F_IN=128, HID=64, OUT=32, E=3.2M edges, EL=1M label edges.
// Inputs: float32 (x, weights, biases), int32 (edge indices).
// Output float32: [link_pred (1M) | z (100000*32)] concatenated flat.
//
// R3: scatter_edges (15x write amplification, 195MB for 12.8MB buffer) replaced
// by 2-level binning: binA appends (row,col) pairs into col>>7 buckets (dense,
// temporally-clustered writes), binB CSR-scatters per bucket with LDS cursors
// into a hot ~16KB L2-resident slice. Bucket bases come free from the node scan.

// ---------------- CSR build ----------------

__global__ __launch_bounds__(256) void hist_kernel(const int* __restrict__ colv,
                                                   int* __restrict__ degi, int E) {
    int e = blockIdx.x * 256 + threadIdx.x;
    if (e < E) atomicAdd(&degi[colv[e]], 1);
}

__global__ __launch_bounds__(256) void dinv_kernel(const int* __restrict__ degi,
                                                   float* __restrict__ dinv, int n) {
    int i = blockIdx.x * 256 + threadIdx.x;
    if (i < n) dinv[i] = rsqrtf((float)(degi[i] + 1));  // +1: self loop
}

// two-level exclusive scan over counts (1024 elements / block)
__global__ __launch_bounds__(256) void scan_pass1(const int* __restrict__ counts,
                                                  int* __restrict__ scanned,
                                                  int* __restrict__ bsum, int n) {
    __shared__ int sh[256];
    int base = blockIdx.x * 1024 + threadIdx.x * 4;
    int v[4]; int tsum = 0;
#pragma unroll
    for (int i = 0; i < 4; ++i) { int idx = base + i; v[i] = (idx < n) ? counts[idx] : 0; tsum += v[i]; }
    sh[threadIdx.x] = tsum;
    __syncthreads();
#pragma unroll
    for (int off = 1; off < 256; off <<= 1) {
        int y = (threadIdx.x >= (unsigned)off) ? sh[threadIdx.x - off] : 0;
        __syncthreads();
        sh[threadIdx.x] += y;
        __syncthreads();
    }
    int ex = sh[threadIdx.x] - tsum;
#pragma unroll
    for (int i = 0; i < 4; ++i) { int idx = base + i; if (idx < n) scanned[idx] = ex; ex += v[i]; }
    if (threadIdx.x == 255) bsum[blockIdx.x] = sh[255];
}

__global__ void scan_pass2(const int* __restrict__ bsum, int* __restrict__ bbase,
                           int nb, int* __restrict__ offsets_last) {
    if (threadIdx.x == 0 && blockIdx.x == 0) {
        int run = 0;
        for (int i = 0; i < nb; ++i) { bbase[i] = run; run += bsum[i]; }
        offsets_last[0] = run;  // offsets[N] = E
    }
}

// finalize offsets; also emit bucket cursors bcur[b] = offsets[b*128]
__global__ __launch_bounds__(256) void scan_pass3(int* __restrict__ offsets,
                                                  const int* __restrict__ bbase,
                                                  int* __restrict__ bcur, int n) {
    int base = blockIdx.x * 1024 + threadIdx.x * 4;
    int add = bbase[blockIdx.x];
#pragma unroll
    for (int i = 0; i < 4; ++i) {
        int idx = base + i;
        if (idx < n) {
            int o = offsets[idx] + add;
            offsets[idx] = o;
            if ((idx & 127) == 0) bcur[idx >> 7] = o;
        }
    }
}

// Phase A: bin (row,col) pairs by bucket = col>>7. Appends are temporally
// clustered per bucket -> 64B lines fill fast -> ~1x write amplification.
__global__ __launch_bounds__(256) void binA_kernel(const int* __restrict__ rowv,
                                                   const int* __restrict__ colv,
                                                   int* __restrict__ bcur,
                                                   int2* __restrict__ pairs, int E) {
    int e = blockIdx.x * 256 + threadIdx.x;
    if (e < E) {
        int c = colv[e];
        int slot = atomicAdd(&bcur[c >> 7], 1);
        pairs[slot] = make_int2(rowv[e], c);
    }
}

// Phase B: one block per bucket (128 nodes); CSR-scatter with LDS cursors into
// the bucket's contiguous CSR slice (~16KB, L2-hot).
__global__ __launch_bounds__(256) void binB_kernel(const int2* __restrict__ pairs,
                                                   const int* __restrict__ offsets,
                                                   int* __restrict__ edge_src, int N) {
    __shared__ int lcur[128];
    int nodeBeg = blockIdx.x << 7;
    int nodeEnd = min(nodeBeg + 128, N);
    int segBeg = offsets[nodeBeg];
    int segEnd = offsets[nodeEnd];
    if (threadIdx.x < (nodeEnd - nodeBeg))
        lcur[threadIdx.x] = offsets[nodeBeg + threadIdx.x] - segBeg;
    __syncthreads();
    for (int e = segBeg + threadIdx.x; e < segEnd; e += 256) {
        int2 pr = pairs[e];
        int rel = atomicAdd(&lcur[pr.y - nodeBeg], 1);
        edge_src[segBeg + rel] = pr.x;
    }
}

// ---------------- GEMM + dinv scale: h'[n][j] = dinv[n] * sum_k in[n][k]*W[k][j] ----------------

template <int K, int NOUT>
__global__ __launch_bounds__(256) void gemm_scale(const float* __restrict__ in_,
                                                  const float* __restrict__ W,
                                                  const float* __restrict__ dinv,
                                                  float* __restrict__ out, int N) {
    __shared__ float Ws[K * NOUT];
    for (int i = threadIdx.x; i < K * NOUT; i += 256) Ws[i] = W[i];
    __syncthreads();
    constexpr int NPB = 256 / NOUT;  // nodes per block
    int node = blockIdx.x * NPB + threadIdx.x / NOUT;
    int j = threadIdx.x % NOUT;
    if (node >= N) return;
    float acc = 0.f;
    const float4* rowp = (const float4*)(in_ + (size_t)node * K);
#pragma unroll
    for (int c = 0; c < K / 4; ++c) {
        float4 v = rowp[c];
        acc = fmaf(v.x, Ws[(c * 4 + 0) * NOUT + j], acc);
        acc = fmaf(v.y, Ws[(c * 4 + 1) * NOUT + j], acc);
        acc = fmaf(v.z, Ws[(c * 4 + 2) * NOUT + j], acc);
        acc = fmaf(v.w, Ws[(c * 4 + 3) * NOUT + j], acc);
    }
    out[(size_t)node * NOUT + j] = acc * dinv[node];
}

// ---------------- Pull aggregation: out[n] = relu?(dinv[n]*(h'[n] + sum h'[src]) + b) ----------------

template <int F, bool RELU>
__global__ __launch_bounds__(256) void agg_pull(const float* __restrict__ h,
                                                const float* __restrict__ dinv,
                                                const float* __restrict__ bias,
                                                const int* __restrict__ edge_src,
                                                const int* __restrict__ offsets,
                                                float* __restrict__ out, int N) {
    int lane = threadIdx.x & 63;
    int wave = blockIdx.x * (256 >> 6) + (threadIdx.x >> 6);
    constexpr int GPW = 64 / F;  // node groups per wave
    int node = wave * GPW + lane / F;
    int f = lane % F;
    if (node >= N) return;
    float dn = dinv[node];
    float acc = h[(size_t)node * F + f];  // self-loop (h' already has dinv[n])
    int beg = offsets[node], end = offsets[node + 1];
    int j = beg;
    for (; j + 8 <= end; j += 8) {
        int s[8];
#pragma unroll
        for (int u = 0; u < 8; ++u) s[u] = edge_src[j + u];
        float v[8];
#pragma unroll
        for (int u = 0; u < 8; ++u) v[u] = h[(size_t)s[u] * F + f];
#pragma unroll
        for (int u = 0; u < 8; ++u) acc += v[u];
    }
    for (; j < end; ++j) acc += h[(size_t)edge_src[j] * F + f];
    float r = acc * dn + bias[f];
    if (RELU) r = fmaxf(r, 0.f);
    out[(size_t)node * F + f] = r;
}

// ---------------- Decode: tiled GEMM. link_pred[e] = relu(ef@W1+b1)@w2 + b2 ----------------

#define DTILE 64

__global__ __launch_bounds__(256) void decode_kernel(const float* __restrict__ z,  // [N,32]
                                                     const int* __restrict__ eli, int EL,
                                                     const float* __restrict__ lpW1,
                                                     const float* __restrict__ lpb1,
                                                     const float* __restrict__ lpW2,
                                                     const float* __restrict__ lpb2,
                                                     float* __restrict__ out) {
    __shared__ float Ws[64 * 64];             // W1[k][j]
    __shared__ float efT[64][DTILE + 4];      // [k][e], +4 pad
    __shared__ float red[16][DTILE + 1];      // j-group partials per edge
    for (int i = threadIdx.x; i < 64 * 64; i += 256) Ws[i] = lpW1[i];

    const int t = threadIdx.x;
    const int e0 = t & 15;   // edge block (4 edges)
    const int j0 = t >> 4;   // col block (4 cols)
    float w2r[4], b1r[4];
#pragma unroll
    for (int i = 0; i < 4; ++i) { w2r[i] = lpW2[j0 * 4 + i]; b1r[i] = lpb1[j0 * 4 + i]; }
    const float b2v = lpb2[0];

    const int r = t >> 1;          // row task 0..127
    const int half = t & 1;        // which 64B half of the 128B row
    const int which = r >> 6;      // 0 -> endpoint A, 1 -> endpoint B
    const int eRow = r & 63;

    const int nTiles = EL / DTILE;
    for (int tile = blockIdx.x; tile < nTiles; tile += gridDim.x) {
        int node = eli[which * EL + tile * DTILE + eRow];
        const float4* zp = (const float4*)(z + (size_t)node * 32) + half * 4;
#pragma unroll
        for (int q = 0; q < 4; ++q) {
            float4 v = zp[q];
            int kk = which * 32 + half * 16 + q * 4;
            efT[kk + 0][eRow] = v.x;
            efT[kk + 1][eRow] = v.y;
            efT[kk + 2][eRow] = v.z;
            efT[kk + 3][eRow] = v.w;
        }
        __syncthreads();

        float acc[4][4];
#pragma unroll
        for (int i = 0; i < 4; ++i)
#pragma unroll
            for (int jj = 0; jj < 4; ++jj) acc[i][jj] = 0.f;
#pragma unroll 8
        for (int k = 0; k < 64; ++k) {
            float4 ef = *(const float4*)&efT[k][e0 * 4];
            float4 wv = *(const float4*)&Ws[k * 64 + j0 * 4];
            acc[0][0] = fmaf(ef.x, wv.x, acc[0][0]);
            acc[0][1] = fmaf(ef.x, wv.y, acc[0][1]);
            acc[0][2] = fmaf(ef.x, wv.z, acc[0][2]);
            acc[0][3] = fmaf(ef.x, wv.w, acc[0][3]);
            acc[1][0] = fmaf(ef.y, wv.x, acc[1][0]);
            acc[1][1] = fmaf(ef.y, wv.y, acc[1][1]);
            acc[1][2] = fmaf(ef.y, wv.z, acc[1][2]);
            acc[1][3] = fmaf(ef.y, wv.w, acc[1][3]);
            acc[2][0] = fmaf(ef.z, wv.x, acc[2][0]);
            acc[2][1] = fmaf(ef.z, wv.y, acc[2][1]);
            acc[2][2] = fmaf(ef.z, wv.z, acc[2][2]);
            acc[2][3] = fmaf(ef.z, wv.w, acc[2][3]);
            acc[3][0] = fmaf(ef.w, wv.x, acc[3][0]);
            acc[3][1] = fmaf(ef.w, wv.y, acc[3][1]);
            acc[3][2] = fmaf(ef.w, wv.z, acc[3][2]);
            acc[3][3] = fmaf(ef.w, wv.w, acc[3][3]);
        }

#pragma unroll
        for (int i = 0; i < 4; ++i) {
            float s = 0.f;
#pragma unroll
            for (int jj = 0; jj < 4; ++jj)
                s = fmaf(fmaxf(acc[i][jj] + b1r[jj], 0.f), w2r[jj], s);
            red[j0][e0 * 4 + i] = s;
        }
        __syncthreads();
        if (t < DTILE) {
            float s = 0.f;
#pragma unroll
            for (int g = 0; g < 16; ++g) s += red[g][t];
            out[tile * DTILE + t] = s + b2v;
        }
    }
}

// ---------------- launch ----------------

extern "C" void kernel_launch(void* const* d_in, const int* in_sizes, int n_in,
                              void* d_out, int out_size, void* d_ws, size_t ws_size,
                              hipStream_t stream) {
    const float* x    = (const float*)d_in[0];
    const int* ei     = (const int*)d_in[1];
    const int* eli    = (const int*)d_in[2];
    const float* W1   = (const float*)d_in[3];
    const float* b1   = (const float*)d_in[4];
    const float* W2   = (const float*)d_in[5];
    const float* b2   = (const float*)d_in[6];
    const float* W3   = (const float*)d_in[7];
    const float* b3   = (const float*)d_in[8];
    const float* lpW1 = (const float*)d_in[9];
    const float* lpb1 = (const float*)d_in[10];
    const float* lpW2 = (const float*)d_in[11];
    const float* lpb2 = (const float*)d_in[12];

    const int N  = in_sizes[0] / 128;   // 100000
    const int E  = in_sizes[1] / 2;     // 3200000
    const int EL = in_sizes[2] / 2;     // 1000000

    char* p = (char*)d_ws;
    auto alloc = [&](size_t bytes) { void* r = (void*)p; p += (bytes + 255) & ~(size_t)255; return r; };
    int*   degi     = (int*)alloc((size_t)N * 4);
    float* dinv     = (float*)alloc((size_t)N * 4);
    int*   offsets  = (int*)alloc((size_t)(N + 1) * 4);
    int*   bcur     = (int*)alloc(1024 * 4);
    int*   bsum     = (int*)alloc(256 * 4);
    int*   bbase    = (int*)alloc(256 * 4);
    int*   edge_src = (int*)alloc((size_t)E * 4);
    float* bufG     = (float*)alloc((size_t)N * 64 * 4);
    float* bufZ     = (float*)alloc((size_t)N * 64 * 4);
    int2*  pairs    = (int2*)bufG;   // alias: pairs lifetime ends before gemm writes bufG

    const int* rowv = ei;        // edge_index[0] = source
    const int* colv = ei + E;    // edge_index[1] = target

    hipMemsetAsync(degi, 0, (size_t)N * 4, stream);
    hist_kernel<<<(E + 255) / 256, 256, 0, stream>>>(colv, degi, E);
    dinv_kernel<<<(N + 255) / 256, 256, 0, stream>>>(degi, dinv, N);
    int nb = (N + 1023) / 1024;  // 98
    scan_pass1<<<nb, 256, 0, stream>>>(degi, offsets, bsum, N);
    scan_pass2<<<1, 64, 0, stream>>>(bsum, bbase, nb, offsets + N);
    scan_pass3<<<nb, 256, 0, stream>>>(offsets, bbase, bcur, N);
    binA_kernel<<<(E + 255) / 256, 256, 0, stream>>>(rowv, colv, bcur, pairs, E);
    int nbuk = (N + 127) / 128;  // 782
    binB_kernel<<<nbuk, 256, 0, stream>>>(pairs, offsets, edge_src, N);

    float* zout = (float*)d_out + EL;   // z lives in the output tail (float32)

    // layer 1: x[N,128] -> bufG h' -> bufZ (relu)
    gemm_scale<128, 64><<<(N + 3) / 4, 256, 0, stream>>>(x, W1, dinv, bufG, N);
    agg_pull<64, true><<<(N + 3) / 4, 256, 0, stream>>>(bufG, dinv, b1, edge_src, offsets, bufZ, N);
    // layer 2
    gemm_scale<64, 64><<<(N + 3) / 4, 256, 0, stream>>>(bufZ, W2, dinv, bufG, N);
    agg_pull<64, true><<<(N + 3) / 4, 256, 0, stream>>>(bufG, dinv, b2, edge_src, offsets, bufZ, N);
    // layer 3: 32-wide, write z directly into d_out tail
    gemm_scale<64, 32><<<(N + 7) / 8, 256, 0, stream>>>(bufZ, W3, dinv, bufG, N);
    agg_pull<32, false><<<(N + 7) / 8, 256, 0, stream>>>(bufG, dinv, b3, edge_src, offsets, zout, N);
    // decode reads z from d_out tail
    decode_kernel<<<1024, 256, 0, stream>>>(zout, eli, EL, lpW1, lpb1, lpW2, lpb2, (float*)d_out);
}

// Round 5
// 970.795 us; speedup vs baseline: 1.7060x; 1.7060x over previous
//
#include <hip/hip_runtime.h>
#include <hip/hip_bf16.h>

// MusicGNN — 3-layer GCN encoder + MLP link predictor.
// N=100000, F_IN=128, HID=64, OUT=32, E=3.2M edges, EL=1M label edges.
// Inputs: float32 (x, weights, biases), int32 (edge indices).
// Output float32: [link_pred (1M) | z (100000*32)] concatenated flat.
//
// R4: binA rewritten as block-local counting sort: LDS histogram over 782
// buckets, ONE global atomicAdd per (block,bucket) run reservation, dense
// run writes (fixes R3's 157MB write amplification + 782-counter global
// contention). Pairs packed to one int: (row<<7)|(col&127).

// ---------------- CSR build ----------------

__global__ __launch_bounds__(256) void hist_kernel(const int* __restrict__ colv,
                                                   int* __restrict__ degi, int E) {
    int e = blockIdx.x * 256 + threadIdx.x;
    if (e < E) atomicAdd(&degi[colv[e]], 1);
}

__global__ __launch_bounds__(256) void dinv_kernel(const int* __restrict__ degi,
                                                   float* __restrict__ dinv, int n) {
    int i = blockIdx.x * 256 + threadIdx.x;
    if (i < n) dinv[i] = rsqrtf((float)(degi[i] + 1));  // +1: self loop
}

// two-level exclusive scan over counts (1024 elements / block)
__global__ __launch_bounds__(256) void scan_pass1(const int* __restrict__ counts,
                                                  int* __restrict__ scanned,
                                                  int* __restrict__ bsum, int n) {
    __shared__ int sh[256];
    int base = blockIdx.x * 1024 + threadIdx.x * 4;
    int v[4]; int tsum = 0;
#pragma unroll
    for (int i = 0; i < 4; ++i) { int idx = base + i; v[i] = (idx < n) ? counts[idx] : 0; tsum += v[i]; }
    sh[threadIdx.x] = tsum;
    __syncthreads();
#pragma unroll
    for (int off = 1; off < 256; off <<= 1) {
        int y = (threadIdx.x >= (unsigned)off) ? sh[threadIdx.x - off] : 0;
        __syncthreads();
        sh[threadIdx.x] += y;
        __syncthreads();
    }
    int ex = sh[threadIdx.x] - tsum;
#pragma unroll
    for (int i = 0; i < 4; ++i) { int idx = base + i; if (idx < n) scanned[idx] = ex; ex += v[i]; }
    if (threadIdx.x == 255) bsum[blockIdx.x] = sh[255];
}

__global__ void scan_pass2(const int* __restrict__ bsum, int* __restrict__ bbase,
                           int nb, int* __restrict__ offsets_last) {
    if (threadIdx.x == 0 && blockIdx.x == 0) {
        int run = 0;
        for (int i = 0; i < nb; ++i) { bbase[i] = run; run += bsum[i]; }
        offsets_last[0] = run;  // offsets[N] = E
    }
}

// finalize offsets; also emit bucket cursors bcur[b] = offsets[b*128]
__global__ __launch_bounds__(256) void scan_pass3(int* __restrict__ offsets,
                                                  const int* __restrict__ bbase,
                                                  int* __restrict__ bcur, int n) {
    int base = blockIdx.x * 1024 + threadIdx.x * 4;
    int add = bbase[blockIdx.x];
#pragma unroll
    for (int i = 0; i < 4; ++i) {
        int idx = base + i;
        if (idx < n) {
            int o = offsets[idx] + add;
            offsets[idx] = o;
            if ((idx & 127) == 0) bcur[idx >> 7] = o;
        }
    }
}

// Phase A: block-local counting sort into buckets (bucket = col>>7).
// One global atomicAdd per (block,bucket); dense run writes; packed pairs.
#define BINA_CHUNK 4096

__global__ __launch_bounds__(256) void binA_kernel(const int* __restrict__ rowv,
                                                   const int* __restrict__ colv,
                                                   int* __restrict__ bcur,
                                                   int* __restrict__ pairs,
                                                   int E, int nbuck) {
    __shared__ int hist[800];
    __shared__ int pos[800];
    int base = blockIdx.x * BINA_CHUNK;
    int end = min(base + BINA_CHUNK, E);
    for (int i = threadIdx.x; i < nbuck; i += 256) hist[i] = 0;
    __syncthreads();
    for (int e = base + threadIdx.x; e < end; e += 256)
        atomicAdd(&hist[colv[e] >> 7], 1);
    __syncthreads();
    for (int b = threadIdx.x; b < nbuck; b += 256) {
        int c = hist[b];
        pos[b] = (c > 0) ? atomicAdd(&bcur[b], c) : 0;  // reserve contiguous run
    }
    __syncthreads();
    for (int e = base + threadIdx.x; e < end; e += 256) {
        int c = colv[e];
        int g = atomicAdd(&pos[c >> 7], 1);            // LDS cursor
        pairs[g] = (rowv[e] << 7) | (c & 127);          // row<2^17 -> fits
    }
}

// Phase B: one block per bucket (128 nodes); CSR-scatter with LDS cursors into
// the bucket's contiguous CSR slice (~16KB, L2-hot).
__global__ __launch_bounds__(256) void binB_kernel(const int* __restrict__ pairs,
                                                   const int* __restrict__ offsets,
                                                   int* __restrict__ edge_src, int N) {
    __shared__ int lcur[128];
    int nodeBeg = blockIdx.x << 7;
    int nodeEnd = min(nodeBeg + 128, N);
    int segBeg = offsets[nodeBeg];
    int segEnd = offsets[nodeEnd];
    if (threadIdx.x < (nodeEnd - nodeBeg))
        lcur[threadIdx.x] = offsets[nodeBeg + threadIdx.x] - segBeg;
    __syncthreads();
    for (int e = segBeg + threadIdx.x; e < segEnd; e += 256) {
        int p = pairs[e];
        int rel = atomicAdd(&lcur[p & 127], 1);
        edge_src[segBeg + rel] = p >> 7;
    }
}

// ---------------- GEMM + dinv scale: h'[n][j] = dinv[n] * sum_k in[n][k]*W[k][j] ----------------

template <int K, int NOUT>
__global__ __launch_bounds__(256) void gemm_scale(const float* __restrict__ in_,
                                                  const float* __restrict__ W,
                                                  const float* __restrict__ dinv,
                                                  float* __restrict__ out, int N) {
    __shared__ float Ws[K * NOUT];
    for (int i = threadIdx.x; i < K * NOUT; i += 256) Ws[i] = W[i];
    __syncthreads();
    constexpr int NPB = 256 / NOUT;  // nodes per block
    int node = blockIdx.x * NPB + threadIdx.x / NOUT;
    int j = threadIdx.x % NOUT;
    if (node >= N) return;
    float acc = 0.f;
    const float4* rowp = (const float4*)(in_ + (size_t)node * K);
#pragma unroll
    for (int c = 0; c < K / 4; ++c) {
        float4 v = rowp[c];
        acc = fmaf(v.x, Ws[(c * 4 + 0) * NOUT + j], acc);
        acc = fmaf(v.y, Ws[(c * 4 + 1) * NOUT + j], acc);
        acc = fmaf(v.z, Ws[(c * 4 + 2) * NOUT + j], acc);
        acc = fmaf(v.w, Ws[(c * 4 + 3) * NOUT + j], acc);
    }
    out[(size_t)node * NOUT + j] = acc * dinv[node];
}

// ---------------- Pull aggregation: out[n] = relu?(dinv[n]*(h'[n] + sum h'[src]) + b) ----------------

template <int F, bool RELU>
__global__ __launch_bounds__(256) void agg_pull(const float* __restrict__ h,
                                                const float* __restrict__ dinv,
                                                const float* __restrict__ bias,
                                                const int* __restrict__ edge_src,
                                                const int* __restrict__ offsets,
                                                float* __restrict__ out, int N) {
    int lane = threadIdx.x & 63;
    int wave = blockIdx.x * (256 >> 6) + (threadIdx.x >> 6);
    constexpr int GPW = 64 / F;  // node groups per wave
    int node = wave * GPW + lane / F;
    int f = lane % F;
    if (node >= N) return;
    float dn = dinv[node];
    float acc = h[(size_t)node * F + f];  // self-loop (h' already has dinv[n])
    int beg = offsets[node], end = offsets[node + 1];
    int j = beg;
    for (; j + 8 <= end; j += 8) {
        int s[8];
#pragma unroll
        for (int u = 0; u < 8; ++u) s[u] = edge_src[j + u];
        float v[8];
#pragma unroll
        for (int u = 0; u < 8; ++u) v[u] = h[(size_t)s[u] * F + f];
#pragma unroll
        for (int u = 0; u < 8; ++u) acc += v[u];
    }
    for (; j < end; ++j) acc += h[(size_t)edge_src[j] * F + f];
    float r = acc * dn + bias[f];
    if (RELU) r = fmaxf(r, 0.f);
    out[(size_t)node * F + f] = r;
}

// ---------------- Decode: tiled GEMM. link_pred[e] = relu(ef@W1+b1)@w2 + b2 ----------------

#define DTILE 64

__global__ __launch_bounds__(256) void decode_kernel(const float* __restrict__ z,  // [N,32]
                                                     const int* __restrict__ eli, int EL,
                                                     const float* __restrict__ lpW1,
                                                     const float* __restrict__ lpb1,
                                                     const float* __restrict__ lpW2,
                                                     const float* __restrict__ lpb2,
                                                     float* __restrict__ out) {
    __shared__ float Ws[64 * 64];             // W1[k][j]
    __shared__ float efT[64][DTILE + 4];      // [k][e], +4 pad
    __shared__ float red[16][DTILE + 1];      // j-group partials per edge
    for (int i = threadIdx.x; i < 64 * 64; i += 256) Ws[i] = lpW1[i];

    const int t = threadIdx.x;
    const int e0 = t & 15;   // edge block (4 edges)
    const int j0 = t >> 4;   // col block (4 cols)
    float w2r[4], b1r[4];
#pragma unroll
    for (int i = 0; i < 4; ++i) { w2r[i] = lpW2[j0 * 4 + i]; b1r[i] = lpb1[j0 * 4 + i]; }
    const float b2v = lpb2[0];

    const int r = t >> 1;          // row task 0..127
    const int half = t & 1;        // which 64B half of the 128B row
    const int which = r >> 6;      // 0 -> endpoint A, 1 -> endpoint B
    const int eRow = r & 63;

    const int nTiles = EL / DTILE;
    for (int tile = blockIdx.x; tile < nTiles; tile += gridDim.x) {
        int node = eli[which * EL + tile * DTILE + eRow];
        const float4* zp = (const float4*)(z + (size_t)node * 32) + half * 4;
#pragma unroll
        for (int q = 0; q < 4; ++q) {
            float4 v = zp[q];
            int kk = which * 32 + half * 16 + q * 4;
            efT[kk + 0][eRow] = v.x;
            efT[kk + 1][eRow] = v.y;
            efT[kk + 2][eRow] = v.z;
            efT[kk + 3][eRow] = v.w;
        }
        __syncthreads();

        float acc[4][4];
#pragma unroll
        for (int i = 0; i < 4; ++i)
#pragma unroll
            for (int jj = 0; jj < 4; ++jj) acc[i][jj] = 0.f;
#pragma unroll 8
        for (int k = 0; k < 64; ++k) {
            float4 ef = *(const float4*)&efT[k][e0 * 4];
            float4 wv = *(const float4*)&Ws[k * 64 + j0 * 4];
            acc[0][0] = fmaf(ef.x, wv.x, acc[0][0]);
            acc[0][1] = fmaf(ef.x, wv.y, acc[0][1]);
            acc[0][2] = fmaf(ef.x, wv.z, acc[0][2]);
            acc[0][3] = fmaf(ef.x, wv.w, acc[0][3]);
            acc[1][0] = fmaf(ef.y, wv.x, acc[1][0]);
            acc[1][1] = fmaf(ef.y, wv.y, acc[1][1]);
            acc[1][2] = fmaf(ef.y, wv.z, acc[1][2]);
            acc[1][3] = fmaf(ef.y, wv.w, acc[1][3]);
            acc[2][0] = fmaf(ef.z, wv.x, acc[2][0]);
            acc[2][1] = fmaf(ef.z, wv.y, acc[2][1]);
            acc[2][2] = fmaf(ef.z, wv.z, acc[2][2]);
            acc[2][3] = fmaf(ef.z, wv.w, acc[2][3]);
            acc[3][0] = fmaf(ef.w, wv.x, acc[3][0]);
            acc[3][1] = fmaf(ef.w, wv.y, acc[3][1]);
            acc[3][2] = fmaf(ef.w, wv.z, acc[3][2]);
            acc[3][3] = fmaf(ef.w, wv.w, acc[3][3]);
        }

#pragma unroll
        for (int i = 0; i < 4; ++i) {
            float s = 0.f;
#pragma unroll
            for (int jj = 0; jj < 4; ++jj)
                s = fmaf(fmaxf(acc[i][jj] + b1r[jj], 0.f), w2r[jj], s);
            red[j0][e0 * 4 + i] = s;
        }
        __syncthreads();
        if (t < DTILE) {
            float s = 0.f;
#pragma unroll
            for (int g = 0; g < 16; ++g) s += red[g][t];
            out[tile * DTILE + t] = s + b2v;
        }
    }
}

// ---------------- launch ----------------

extern "C" void kernel_launch(void* const* d_in, const int* in_sizes, int n_in,
                              void* d_out, int out_size, void* d_ws, size_t ws_size,
                              hipStream_t stream) {
    const float* x    = (const float*)d_in[0];
    const int* ei     = (const int*)d_in[1];
    const int* eli    = (const int*)d_in[2];
    const float* W1   = (const float*)d_in[3];
    const float* b1   = (const float*)d_in[4];
    const float* W2   = (const float*)d_in[5];
    const float* b2   = (const float*)d_in[6];
    const float* W3   = (const float*)d_in[7];
    const float* b3   = (const float*)d_in[8];
    const float* lpW1 = (const float*)d_in[9];
    const float* lpb1 = (const float*)d_in[10];
    const float* lpW2 = (const float*)d_in[11];
    const float* lpb2 = (const float*)d_in[12];

    const int N  = in_sizes[0] / 128;   // 100000
    const int E  = in_sizes[1] / 2;     // 3200000
    const int EL = in_sizes[2] / 2;     // 1000000

    char* p = (char*)d_ws;
    auto alloc = [&](size_t bytes) { void* r = (void*)p; p += (bytes + 255) & ~(size_t)255; return r; };
    int*   degi     = (int*)alloc((size_t)N * 4);
    float* dinv     = (float*)alloc((size_t)N * 4);
    int*   offsets  = (int*)alloc((size_t)(N + 1) * 4);
    int*   bcur     = (int*)alloc(1024 * 4);
    int*   bsum     = (int*)alloc(256 * 4);
    int*   bbase    = (int*)alloc(256 * 4);
    int*   edge_src = (int*)alloc((size_t)E * 4);
    float* bufG     = (float*)alloc((size_t)N * 64 * 4);
    float* bufZ     = (float*)alloc((size_t)N * 64 * 4);
    int*   pairs    = (int*)bufG;   // alias: pairs lifetime ends before gemm writes bufG

    const int* rowv = ei;        // edge_index[0] = source
    const int* colv = ei + E;    // edge_index[1] = target

    hipMemsetAsync(degi, 0, (size_t)N * 4, stream);
    hist_kernel<<<(E + 255) / 256, 256, 0, stream>>>(colv, degi, E);
    dinv_kernel<<<(N + 255) / 256, 256, 0, stream>>>(degi, dinv, N);
    int nb = (N + 1023) / 1024;  // 98
    scan_pass1<<<nb, 256, 0, stream>>>(degi, offsets, bsum, N);
    scan_pass2<<<1, 64, 0, stream>>>(bsum, bbase, nb, offsets + N);
    scan_pass3<<<nb, 256, 0, stream>>>(offsets, bbase, bcur, N);
    int nbuk = (N + 127) / 128;  // 782
    binA_kernel<<<(E + BINA_CHUNK - 1) / BINA_CHUNK, 256, 0, stream>>>(rowv, colv, bcur, pairs, E, nbuk);
    binB_kernel<<<nbuk, 256, 0, stream>>>(pairs, offsets, edge_src, N);

    float* zout = (float*)d_out + EL;   // z lives in the output tail (float32)

    // layer 1: x[N,128] -> bufG h' -> bufZ (relu)
    gemm_scale<128, 64><<<(N + 3) / 4, 256, 0, stream>>>(x, W1, dinv, bufG, N);
    agg_pull<64, true><<<(N + 3) / 4, 256, 0, stream>>>(bufG, dinv, b1, edge_src, offsets, bufZ, N);
    // layer 2
    gemm_scale<64, 64><<<(N + 3) / 4, 256, 0, stream>>>(bufZ, W2, dinv, bufG, N);
    agg_pull<64, true><<<(N + 3) / 4, 256, 0, stream>>>(bufG, dinv, b2, edge_src, offsets, bufZ, N);
    // layer 3: 32-wide, write z directly into d_out tail
    gemm_scale<64, 32><<<(N + 7) / 8, 256, 0, stream>>>(bufZ, W3, dinv, bufG, N);
    agg_pull<32, false><<<(N + 7) / 8, 256, 0, stream>>>(bufG, dinv, b3, edge_src, offsets, zout, N);
    // decode reads z from d_out tail
    decode_kernel<<<1024, 256, 0, stream>>>(zout, eli, EL, lpW1, lpb1, lpW2, lpb2, (float*)d_out);
}

// Round 6
// 861.866 us; speedup vs baseline: 1.9216x; 1.1264x over previous
//
#include <hip/hip_runtime.h>
#include <hip/hip_bf16.h>

// MusicGNN — 3-layer GCN encoder + MLP link predictor.
// N=100000, F_IN=128, HID=64, OUT=32, E=3.2M edges, EL=1M label edges.
// Inputs: float32 (x, weights, biases), int32 (edge indices).
// Output float32: [link_pred (1M) | z (100000*32)] concatenated flat.
//
// R5: gemm_scale was LDS-scalar-read bound (128 ds_read_b32 per output; model
// ~121us matches 147us measured). Rewritten as 64-node tiles with 4x4 register
// blocking: per k-chunk 8x ds_read_b128 -> 64 FMA (LDS B/FMA 4 -> 1).

// ---------------- CSR build ----------------

__global__ __launch_bounds__(256) void hist_kernel(const int* __restrict__ colv,
                                                   int* __restrict__ degi, int E) {
    int e = blockIdx.x * 256 + threadIdx.x;
    if (e < E) atomicAdd(&degi[colv[e]], 1);
}

__global__ __launch_bounds__(256) void dinv_kernel(const int* __restrict__ degi,
                                                   float* __restrict__ dinv, int n) {
    int i = blockIdx.x * 256 + threadIdx.x;
    if (i < n) dinv[i] = rsqrtf((float)(degi[i] + 1));  // +1: self loop
}

// two-level exclusive scan over counts (1024 elements / block)
__global__ __launch_bounds__(256) void scan_pass1(const int* __restrict__ counts,
                                                  int* __restrict__ scanned,
                                                  int* __restrict__ bsum, int n) {
    __shared__ int sh[256];
    int base = blockIdx.x * 1024 + threadIdx.x * 4;
    int v[4]; int tsum = 0;
#pragma unroll
    for (int i = 0; i < 4; ++i) { int idx = base + i; v[i] = (idx < n) ? counts[idx] : 0; tsum += v[i]; }
    sh[threadIdx.x] = tsum;
    __syncthreads();
#pragma unroll
    for (int off = 1; off < 256; off <<= 1) {
        int y = (threadIdx.x >= (unsigned)off) ? sh[threadIdx.x - off] : 0;
        __syncthreads();
        sh[threadIdx.x] += y;
        __syncthreads();
    }
    int ex = sh[threadIdx.x] - tsum;
#pragma unroll
    for (int i = 0; i < 4; ++i) { int idx = base + i; if (idx < n) scanned[idx] = ex; ex += v[i]; }
    if (threadIdx.x == 255) bsum[blockIdx.x] = sh[255];
}

__global__ void scan_pass2(const int* __restrict__ bsum, int* __restrict__ bbase,
                           int nb, int* __restrict__ offsets_last) {
    if (threadIdx.x == 0 && blockIdx.x == 0) {
        int run = 0;
        for (int i = 0; i < nb; ++i) { bbase[i] = run; run += bsum[i]; }
        offsets_last[0] = run;  // offsets[N] = E
    }
}

// finalize offsets; also emit bucket cursors bcur[b] = offsets[b*128]
__global__ __launch_bounds__(256) void scan_pass3(int* __restrict__ offsets,
                                                  const int* __restrict__ bbase,
                                                  int* __restrict__ bcur, int n) {
    int base = blockIdx.x * 1024 + threadIdx.x * 4;
    int add = bbase[blockIdx.x];
#pragma unroll
    for (int i = 0; i < 4; ++i) {
        int idx = base + i;
        if (idx < n) {
            int o = offsets[idx] + add;
            offsets[idx] = o;
            if ((idx & 127) == 0) bcur[idx >> 7] = o;
        }
    }
}

// Phase A: block-local counting sort into buckets (bucket = col>>7).
#define BINA_CHUNK 4096

__global__ __launch_bounds__(256) void binA_kernel(const int* __restrict__ rowv,
                                                   const int* __restrict__ colv,
                                                   int* __restrict__ bcur,
                                                   int* __restrict__ pairs,
                                                   int E, int nbuck) {
    __shared__ int hist[800];
    __shared__ int pos[800];
    int base = blockIdx.x * BINA_CHUNK;
    int end = min(base + BINA_CHUNK, E);
    for (int i = threadIdx.x; i < nbuck; i += 256) hist[i] = 0;
    __syncthreads();
    for (int e = base + threadIdx.x; e < end; e += 256)
        atomicAdd(&hist[colv[e] >> 7], 1);
    __syncthreads();
    for (int b = threadIdx.x; b < nbuck; b += 256) {
        int c = hist[b];
        pos[b] = (c > 0) ? atomicAdd(&bcur[b], c) : 0;  // reserve contiguous run
    }
    __syncthreads();
    for (int e = base + threadIdx.x; e < end; e += 256) {
        int c = colv[e];
        int g = atomicAdd(&pos[c >> 7], 1);            // LDS cursor
        pairs[g] = (rowv[e] << 7) | (c & 127);          // row<2^17 -> fits
    }
}

// Phase B: one block per bucket (128 nodes); CSR-scatter with LDS cursors.
__global__ __launch_bounds__(256) void binB_kernel(const int* __restrict__ pairs,
                                                   const int* __restrict__ offsets,
                                                   int* __restrict__ edge_src, int N) {
    __shared__ int lcur[128];
    int nodeBeg = blockIdx.x << 7;
    int nodeEnd = min(nodeBeg + 128, N);
    int segBeg = offsets[nodeBeg];
    int segEnd = offsets[nodeEnd];
    if (threadIdx.x < (nodeEnd - nodeBeg))
        lcur[threadIdx.x] = offsets[nodeBeg + threadIdx.x] - segBeg;
    __syncthreads();
    for (int e = segBeg + threadIdx.x; e < segEnd; e += 256) {
        int p = pairs[e];
        int rel = atomicAdd(&lcur[p & 127], 1);
        edge_src[segBeg + rel] = p >> 7;
    }
}

// ---------------- GEMM + dinv scale: h'[n][j] = dinv[n] * sum_k in[n][k]*W[k][j] ----------------
// 64-node tile, 4x4 register blocking. Thread (ng=tid/(NOUT/4), jg=tid%(NOUT/4))
// owns nodes ng*4..+3, cols jg*4..+3. Per k-chunk of 4: 8 ds_read_b128 -> 64 FMA.

template <int K, int NOUT>
__global__ __launch_bounds__(16 * (NOUT / 4)) void gemm_scale(const float* __restrict__ in_,
                                                              const float* __restrict__ W,
                                                              const float* __restrict__ dinv,
                                                              float* __restrict__ out, int N) {
    constexpr int TPB = 16 * (NOUT / 4);
    constexpr int XPITCH = K + 4;               // +4 floats: break power-of-2 bank stride
    __shared__ float xs[64 * XPITCH];
    __shared__ float ws[K * NOUT];

    const int tid = threadIdx.x;
    const int nodeBase = blockIdx.x * 64;

    // stage W (coalesced float4 -> b128 writes)
    for (int i = tid; i < K * NOUT / 4; i += TPB)
        *(float4*)&ws[i * 4] = *(const float4*)&W[i * 4];
    // stage x tile (row-major, no transpose; clamp tail rows)
    for (int i = tid; i < 64 * K / 4; i += TPB) {
        int row = i / (K / 4), c = i % (K / 4);
        int src = nodeBase + row; if (src >= N) src = N - 1;
        *(float4*)&xs[row * XPITCH + c * 4] = *(const float4*)&in_[(size_t)src * K + c * 4];
    }
    __syncthreads();

    const int jg = tid % (NOUT / 4);
    const int ng = tid / (NOUT / 4);            // 0..15

    float acc[4][4];
#pragma unroll
    for (int i = 0; i < 4; ++i)
#pragma unroll
        for (int j = 0; j < 4; ++j) acc[i][j] = 0.f;

    for (int kc = 0; kc < K / 4; ++kc) {
        float4 xv[4], wv[4];
#pragma unroll
        for (int ni = 0; ni < 4; ++ni)
            xv[ni] = *(const float4*)&xs[(ng * 4 + ni) * XPITCH + kc * 4];
#pragma unroll
        for (int t = 0; t < 4; ++t)
            wv[t] = *(const float4*)&ws[(kc * 4 + t) * NOUT + jg * 4];
#pragma unroll
        for (int ni = 0; ni < 4; ++ni) {
            acc[ni][0] = fmaf(xv[ni].x, wv[0].x, acc[ni][0]);
            acc[ni][1] = fmaf(xv[ni].x, wv[0].y, acc[ni][1]);
            acc[ni][2] = fmaf(xv[ni].x, wv[0].z, acc[ni][2]);
            acc[ni][3] = fmaf(xv[ni].x, wv[0].w, acc[ni][3]);
            acc[ni][0] = fmaf(xv[ni].y, wv[1].x, acc[ni][0]);
            acc[ni][1] = fmaf(xv[ni].y, wv[1].y, acc[ni][1]);
            acc[ni][2] = fmaf(xv[ni].y, wv[1].z, acc[ni][2]);
            acc[ni][3] = fmaf(xv[ni].y, wv[1].w, acc[ni][3]);
            acc[ni][0] = fmaf(xv[ni].z, wv[2].x, acc[ni][0]);
            acc[ni][1] = fmaf(xv[ni].z, wv[2].y, acc[ni][1]);
            acc[ni][2] = fmaf(xv[ni].z, wv[2].z, acc[ni][2]);
            acc[ni][3] = fmaf(xv[ni].z, wv[2].w, acc[ni][3]);
            acc[ni][0] = fmaf(xv[ni].w, wv[3].x, acc[ni][0]);
            acc[ni][1] = fmaf(xv[ni].w, wv[3].y, acc[ni][1]);
            acc[ni][2] = fmaf(xv[ni].w, wv[3].z, acc[ni][2]);
            acc[ni][3] = fmaf(xv[ni].w, wv[3].w, acc[ni][3]);
        }
    }

#pragma unroll
    for (int ni = 0; ni < 4; ++ni) {
        int node = nodeBase + ng * 4 + ni;
        if (node < N) {
            float dn = dinv[node];
            float4 r = make_float4(acc[ni][0] * dn, acc[ni][1] * dn,
                                   acc[ni][2] * dn, acc[ni][3] * dn);
            *(float4*)&out[(size_t)node * NOUT + jg * 4] = r;
        }
    }
}

// ---------------- Pull aggregation: out[n] = relu?(dinv[n]*(h'[n] + sum h'[src]) + b) ----------------

template <int F, bool RELU>
__global__ __launch_bounds__(256) void agg_pull(const float* __restrict__ h,
                                                const float* __restrict__ dinv,
                                                const float* __restrict__ bias,
                                                const int* __restrict__ edge_src,
                                                const int* __restrict__ offsets,
                                                float* __restrict__ out, int N) {
    int lane = threadIdx.x & 63;
    int wave = blockIdx.x * (256 >> 6) + (threadIdx.x >> 6);
    constexpr int GPW = 64 / F;  // node groups per wave
    int node = wave * GPW + lane / F;
    int f = lane % F;
    if (node >= N) return;
    float dn = dinv[node];
    float acc = h[(size_t)node * F + f];  // self-loop (h' already has dinv[n])
    int beg = offsets[node], end = offsets[node + 1];
    int j = beg;
    for (; j + 8 <= end; j += 8) {
        int s[8];
#pragma unroll
        for (int u = 0; u < 8; ++u) s[u] = edge_src[j + u];
        float v[8];
#pragma unroll
        for (int u = 0; u < 8; ++u) v[u] = h[(size_t)s[u] * F + f];
#pragma unroll
        for (int u = 0; u < 8; ++u) acc += v[u];
    }
    for (; j < end; ++j) acc += h[(size_t)edge_src[j] * F + f];
    float r = acc * dn + bias[f];
    if (RELU) r = fmaxf(r, 0.f);
    out[(size_t)node * F + f] = r;
}

// ---------------- Decode: tiled GEMM. link_pred[e] = relu(ef@W1+b1)@w2 + b2 ----------------

#define DTILE 64

__global__ __launch_bounds__(256) void decode_kernel(const float* __restrict__ z,  // [N,32]
                                                     const int* __restrict__ eli, int EL,
                                                     const float* __restrict__ lpW1,
                                                     const float* __restrict__ lpb1,
                                                     const float* __restrict__ lpW2,
                                                     const float* __restrict__ lpb2,
                                                     float* __restrict__ out) {
    __shared__ float Ws[64 * 64];             // W1[k][j]
    __shared__ float efT[64][DTILE + 4];      // [k][e], +4 pad
    __shared__ float red[16][DTILE + 1];      // j-group partials per edge
    for (int i = threadIdx.x; i < 64 * 64; i += 256) Ws[i] = lpW1[i];

    const int t = threadIdx.x;
    const int e0 = t & 15;   // edge block (4 edges)
    const int j0 = t >> 4;   // col block (4 cols)
    float w2r[4], b1r[4];
#pragma unroll
    for (int i = 0; i < 4; ++i) { w2r[i] = lpW2[j0 * 4 + i]; b1r[i] = lpb1[j0 * 4 + i]; }
    const float b2v = lpb2[0];

    const int r = t >> 1;          // row task 0..127
    const int half = t & 1;        // which 64B half of the 128B row
    const int which = r >> 6;      // 0 -> endpoint A, 1 -> endpoint B
    const int eRow = r & 63;

    const int nTiles = EL / DTILE;
    for (int tile = blockIdx.x; tile < nTiles; tile += gridDim.x) {
        int node = eli[which * EL + tile * DTILE + eRow];
        const float4* zp = (const float4*)(z + (size_t)node * 32) + half * 4;
#pragma unroll
        for (int q = 0; q < 4; ++q) {
            float4 v = zp[q];
            int kk = which * 32 + half * 16 + q * 4;
            efT[kk + 0][eRow] = v.x;
            efT[kk + 1][eRow] = v.y;
            efT[kk + 2][eRow] = v.z;
            efT[kk + 3][eRow] = v.w;
        }
        __syncthreads();

        float acc[4][4];
#pragma unroll
        for (int i = 0; i < 4; ++i)
#pragma unroll
            for (int jj = 0; jj < 4; ++jj) acc[i][jj] = 0.f;
#pragma unroll 8
        for (int k = 0; k < 64; ++k) {
            float4 ef = *(const float4*)&efT[k][e0 * 4];
            float4 wv = *(const float4*)&Ws[k * 64 + j0 * 4];
            acc[0][0] = fmaf(ef.x, wv.x, acc[0][0]);
            acc[0][1] = fmaf(ef.x, wv.y, acc[0][1]);
            acc[0][2] = fmaf(ef.x, wv.z, acc[0][2]);
            acc[0][3] = fmaf(ef.x, wv.w, acc[0][3]);
            acc[1][0] = fmaf(ef.y, wv.x, acc[1][0]);
            acc[1][1] = fmaf(ef.y, wv.y, acc[1][1]);
            acc[1][2] = fmaf(ef.y, wv.z, acc[1][2]);
            acc[1][3] = fmaf(ef.y, wv.w, acc[1][3]);
            acc[2][0] = fmaf(ef.z, wv.x, acc[2][0]);
            acc[2][1] = fmaf(ef.z, wv.y, acc[2][1]);
            acc[2][2] = fmaf(ef.z, wv.z, acc[2][2]);
            acc[2][3] = fmaf(ef.z, wv.w, acc[2][3]);
            acc[3][0] = fmaf(ef.w, wv.x, acc[3][0]);
            acc[3][1] = fmaf(ef.w, wv.y, acc[3][1]);
            acc[3][2] = fmaf(ef.w, wv.z, acc[3][2]);
            acc[3][3] = fmaf(ef.w, wv.w, acc[3][3]);
        }

#pragma unroll
        for (int i = 0; i < 4; ++i) {
            float s = 0.f;
#pragma unroll
            for (int jj = 0; jj < 4; ++jj)
                s = fmaf(fmaxf(acc[i][jj] + b1r[jj], 0.f), w2r[jj], s);
            red[j0][e0 * 4 + i] = s;
        }
        __syncthreads();
        if (t < DTILE) {
            float s = 0.f;
#pragma unroll
            for (int g = 0; g < 16; ++g) s += red[g][t];
            out[tile * DTILE + t] = s + b2v;
        }
    }
}

// ---------------- launch ----------------

extern "C" void kernel_launch(void* const* d_in, const int* in_sizes, int n_in,
                              void* d_out, int out_size, void* d_ws, size_t ws_size,
                              hipStream_t stream) {
    const float* x    = (const float*)d_in[0];
    const int* ei     = (const int*)d_in[1];
    const int* eli    = (const int*)d_in[2];
    const float* W1   = (const float*)d_in[3];
    const float* b1   = (const float*)d_in[4];
    const float* W2   = (const float*)d_in[5];
    const float* b2   = (const float*)d_in[6];
    const float* W3   = (const float*)d_in[7];
    const float* b3   = (const float*)d_in[8];
    const float* lpW1 = (const float*)d_in[9];
    const float* lpb1 = (const float*)d_in[10];
    const float* lpW2 = (const float*)d_in[11];
    const float* lpb2 = (const float*)d_in[12];

    const int N  = in_sizes[0] / 128;   // 100000
    const int E  = in_sizes[1] / 2;     // 3200000
    const int EL = in_sizes[2] / 2;     // 1000000

    char* p = (char*)d_ws;
    auto alloc = [&](size_t bytes) { void* r = (void*)p; p += (bytes + 255) & ~(size_t)255; return r; };
    int*   degi     = (int*)alloc((size_t)N * 4);
    float* dinv     = (float*)alloc((size_t)N * 4);
    int*   offsets  = (int*)alloc((size_t)(N + 1) * 4);
    int*   bcur     = (int*)alloc(1024 * 4);
    int*   bsum     = (int*)alloc(256 * 4);
    int*   bbase    = (int*)alloc(256 * 4);
    int*   edge_src = (int*)alloc((size_t)E * 4);
    float* bufG     = (float*)alloc((size_t)N * 64 * 4);
    float* bufZ     = (float*)alloc((size_t)N * 64 * 4);
    int*   pairs    = (int*)bufG;   // alias: pairs lifetime ends before gemm writes bufG

    const int* rowv = ei;        // edge_index[0] = source
    const int* colv = ei + E;    // edge_index[1] = target

    hipMemsetAsync(degi, 0, (size_t)N * 4, stream);
    hist_kernel<<<(E + 255) / 256, 256, 0, stream>>>(colv, degi, E);
    dinv_kernel<<<(N + 255) / 256, 256, 0, stream>>>(degi, dinv, N);
    int nb = (N + 1023) / 1024;  // 98
    scan_pass1<<<nb, 256, 0, stream>>>(degi, offsets, bsum, N);
    scan_pass2<<<1, 64, 0, stream>>>(bsum, bbase, nb, offsets + N);
    scan_pass3<<<nb, 256, 0, stream>>>(offsets, bbase, bcur, N);
    int nbuk = (N + 127) / 128;  // 782
    binA_kernel<<<(E + BINA_CHUNK - 1) / BINA_CHUNK, 256, 0, stream>>>(rowv, colv, bcur, pairs, E, nbuk);
    binB_kernel<<<nbuk, 256, 0, stream>>>(pairs, offsets, edge_src, N);

    float* zout = (float*)d_out + EL;   // z lives in the output tail (float32)

    int gblocks = (N + 63) / 64;  // 1563

    // layer 1: x[N,128] -> bufG h' -> bufZ (relu)
    gemm_scale<128, 64><<<gblocks, 256, 0, stream>>>(x, W1, dinv, bufG, N);
    agg_pull<64, true><<<(N + 3) / 4, 256, 0, stream>>>(bufG, dinv, b1, edge_src, offsets, bufZ, N);
    // layer 2
    gemm_scale<64, 64><<<gblocks, 256, 0, stream>>>(bufZ, W2, dinv, bufG, N);
    agg_pull<64, true><<<(N + 3) / 4, 256, 0, stream>>>(bufG, dinv, b2, edge_src, offsets, bufZ, N);
    // layer 3: 32-wide, write z directly into d_out tail
    gemm_scale<64, 32><<<gblocks, 128, 0, stream>>>(bufZ, W3, dinv, bufG, N);
    agg_pull<32, false><<<(N + 7) / 8, 256, 0, stream>>>(bufG, dinv, b3, edge_src, offsets, zout, N);
    // decode reads z from d_out tail
    decode_kernel<<<1024, 256, 0, stream>>>(zout, eli, EL, lpW1, lpb1, lpW2, lpb2, (float*)d_out);
}

// Round 7
// 742.390 us; speedup vs baseline: 2.2309x; 1.1609x over previous
//
#include <hip/hip_runtime.h>
#include <hip/hip_bf16.h>

// MusicGNN — 3-layer GCN encoder + MLP link predictor.
// N=100000, F_IN=128, HID=64, OUT=32, E=3.2M edges, EL=1M label edges.
// Inputs: float32 (x, weights, biases), int32 (edge indices).
// Output float32: [link_pred (1M) | z (100000*32)] concatenated flat.
//
// R6: hist_kernel (3.2M global atomics, 99.8MB WRITE_SIZE for a 400KB buffer)
// eliminated. Degrees/offsets/dinv now come from the binning pipeline itself:
// bhist (LDS bucket hist, 1 atomic per block-bucket) -> bscan (782-wide) ->
// binA (unchanged) -> binB (per-bucket LDS node hist + scan; writes offsets,
// dinv, edge_src — all coalesced or L2-hot).

#define BINA_CHUNK 4096

// ---------------- bucket histogram: bcount[b] += per-block LDS hist ----------------

__global__ __launch_bounds__(256) void bhist_kernel(const int* __restrict__ colv,
                                                    int* __restrict__ bcount,
                                                    int E, int nbuck) {
    __shared__ int hist[800];
    int base = blockIdx.x * BINA_CHUNK;
    int end = min(base + BINA_CHUNK, E);
    for (int i = threadIdx.x; i < nbuck; i += 256) hist[i] = 0;
    __syncthreads();
    for (int e = base + threadIdx.x; e < end; e += 256)
        atomicAdd(&hist[colv[e] >> 7], 1);
    __syncthreads();
    for (int b = threadIdx.x; b < nbuck; b += 256) {
        int c = hist[b];
        if (c > 0) atomicAdd(&bcount[b], c);
    }
}

// ---------------- bucket scan: bbase/bcur = exscan(bcount); offsets[N]=E ----------------

__global__ __launch_bounds__(256) void bscan_kernel(const int* __restrict__ bcount,
                                                    int* __restrict__ bbase,
                                                    int* __restrict__ bcur,
                                                    int nbuck, int* __restrict__ offsets, int N) {
    __shared__ int sh[256];
    int base = threadIdx.x * 4;
    int v[4]; int tsum = 0;
#pragma unroll
    for (int i = 0; i < 4; ++i) { int idx = base + i; v[i] = (idx < nbuck) ? bcount[idx] : 0; tsum += v[i]; }
    sh[threadIdx.x] = tsum;
    __syncthreads();
#pragma unroll
    for (int off = 1; off < 256; off <<= 1) {
        int y = (threadIdx.x >= (unsigned)off) ? sh[threadIdx.x - off] : 0;
        __syncthreads();
        sh[threadIdx.x] += y;
        __syncthreads();
    }
    int ex = sh[threadIdx.x] - tsum;
#pragma unroll
    for (int i = 0; i < 4; ++i) {
        int idx = base + i;
        if (idx < nbuck) { bbase[idx] = ex; bcur[idx] = ex; ex += v[i]; }
        else if (idx == nbuck) { bbase[idx] = ex; offsets[N] = ex; }  // = E
    }
}

// ---------------- Phase A: block-local counting sort into buckets ----------------

__global__ __launch_bounds__(256) void binA_kernel(const int* __restrict__ rowv,
                                                   const int* __restrict__ colv,
                                                   int* __restrict__ bcur,
                                                   int* __restrict__ pairs,
                                                   int E, int nbuck) {
    __shared__ int hist[800];
    __shared__ int pos[800];
    int base = blockIdx.x * BINA_CHUNK;
    int end = min(base + BINA_CHUNK, E);
    for (int i = threadIdx.x; i < nbuck; i += 256) hist[i] = 0;
    __syncthreads();
    for (int e = base + threadIdx.x; e < end; e += 256)
        atomicAdd(&hist[colv[e] >> 7], 1);
    __syncthreads();
    for (int b = threadIdx.x; b < nbuck; b += 256) {
        int c = hist[b];
        pos[b] = (c > 0) ? atomicAdd(&bcur[b], c) : 0;  // reserve contiguous run
    }
    __syncthreads();
    for (int e = base + threadIdx.x; e < end; e += 256) {
        int c = colv[e];
        int g = atomicAdd(&pos[c >> 7], 1);            // LDS cursor
        pairs[g] = (rowv[e] << 7) | (c & 127);          // row<2^17 -> fits
    }
}

// ---------------- Phase B: per bucket — node hist, scan, offsets+dinv, scatter ----------------

__global__ __launch_bounds__(256) void binB_kernel(const int* __restrict__ pairs,
                                                   const int* __restrict__ bbase,
                                                   int* __restrict__ offsets,
                                                   float* __restrict__ dinv,
                                                   int* __restrict__ edge_src, int N) {
    __shared__ int lcnt[128];
    __shared__ int sc[128];
    __shared__ int lcur[128];
    int nodeBeg = blockIdx.x << 7;
    int segBeg = bbase[blockIdx.x];
    int segEnd = bbase[blockIdx.x + 1];
    if (threadIdx.x < 128) lcnt[threadIdx.x] = 0;
    __syncthreads();
    // pass 1: node histogram
    for (int e = segBeg + threadIdx.x; e < segEnd; e += 256)
        atomicAdd(&lcnt[pairs[e] & 127], 1);
    __syncthreads();
    // 128-wide exclusive scan (Hillis-Steele)
    int v = (threadIdx.x < 128) ? lcnt[threadIdx.x] : 0;
    if (threadIdx.x < 128) sc[threadIdx.x] = v;
    __syncthreads();
    for (int off = 1; off < 128; off <<= 1) {
        int y = 0;
        if (threadIdx.x < 128 && threadIdx.x >= (unsigned)off) y = sc[threadIdx.x - off];
        __syncthreads();
        if (threadIdx.x < 128) sc[threadIdx.x] += y;
        __syncthreads();
    }
    if (threadIdx.x < 128) {
        int ex = sc[threadIdx.x] - v;
        lcur[threadIdx.x] = ex;
        int node = nodeBeg + threadIdx.x;
        if (node < N) {
            offsets[node] = segBeg + ex;              // coalesced
            dinv[node] = rsqrtf((float)(v + 1));      // +1: self loop
        }
    }
    __syncthreads();
    // pass 2: scatter (bucket slice is L2-hot)
    for (int e = segBeg + threadIdx.x; e < segEnd; e += 256) {
        int p = pairs[e];
        int rel = atomicAdd(&lcur[p & 127], 1);
        edge_src[segBeg + rel] = p >> 7;
    }
}

// ---------------- GEMM + dinv scale: h'[n][j] = dinv[n] * sum_k in[n][k]*W[k][j] ----------------
// 64-node tile, 4x4 register blocking. Per k-chunk of 4: 8 ds_read_b128 -> 64 FMA.

template <int K, int NOUT>
__global__ __launch_bounds__(16 * (NOUT / 4)) void gemm_scale(const float* __restrict__ in_,
                                                              const float* __restrict__ W,
                                                              const float* __restrict__ dinv,
                                                              float* __restrict__ out, int N) {
    constexpr int TPB = 16 * (NOUT / 4);
    constexpr int XPITCH = K + 4;               // +4 floats: break power-of-2 bank stride
    __shared__ float xs[64 * XPITCH];
    __shared__ float ws[K * NOUT];

    const int tid = threadIdx.x;
    const int nodeBase = blockIdx.x * 64;

    for (int i = tid; i < K * NOUT / 4; i += TPB)
        *(float4*)&ws[i * 4] = *(const float4*)&W[i * 4];
    for (int i = tid; i < 64 * K / 4; i += TPB) {
        int row = i / (K / 4), c = i % (K / 4);
        int src = nodeBase + row; if (src >= N) src = N - 1;
        *(float4*)&xs[row * XPITCH + c * 4] = *(const float4*)&in_[(size_t)src * K + c * 4];
    }
    __syncthreads();

    const int jg = tid % (NOUT / 4);
    const int ng = tid / (NOUT / 4);            // 0..15

    float acc[4][4];
#pragma unroll
    for (int i = 0; i < 4; ++i)
#pragma unroll
        for (int j = 0; j < 4; ++j) acc[i][j] = 0.f;

    for (int kc = 0; kc < K / 4; ++kc) {
        float4 xv[4], wv[4];
#pragma unroll
        for (int ni = 0; ni < 4; ++ni)
            xv[ni] = *(const float4*)&xs[(ng * 4 + ni) * XPITCH + kc * 4];
#pragma unroll
        for (int t = 0; t < 4; ++t)
            wv[t] = *(const float4*)&ws[(kc * 4 + t) * NOUT + jg * 4];
#pragma unroll
        for (int ni = 0; ni < 4; ++ni) {
            acc[ni][0] = fmaf(xv[ni].x, wv[0].x, acc[ni][0]);
            acc[ni][1] = fmaf(xv[ni].x, wv[0].y, acc[ni][1]);
            acc[ni][2] = fmaf(xv[ni].x, wv[0].z, acc[ni][2]);
            acc[ni][3] = fmaf(xv[ni].x, wv[0].w, acc[ni][3]);
            acc[ni][0] = fmaf(xv[ni].y, wv[1].x, acc[ni][0]);
            acc[ni][1] = fmaf(xv[ni].y, wv[1].y, acc[ni][1]);
            acc[ni][2] = fmaf(xv[ni].y, wv[1].z, acc[ni][2]);
            acc[ni][3] = fmaf(xv[ni].y, wv[1].w, acc[ni][3]);
            acc[ni][0] = fmaf(xv[ni].z, wv[2].x, acc[ni][0]);
            acc[ni][1] = fmaf(xv[ni].z, wv[2].y, acc[ni][1]);
            acc[ni][2] = fmaf(xv[ni].z, wv[2].z, acc[ni][2]);
            acc[ni][3] = fmaf(xv[ni].z, wv[2].w, acc[ni][3]);
            acc[ni][0] = fmaf(xv[ni].w, wv[3].x, acc[ni][0]);
            acc[ni][1] = fmaf(xv[ni].w, wv[3].y, acc[ni][1]);
            acc[ni][2] = fmaf(xv[ni].w, wv[3].z, acc[ni][2]);
            acc[ni][3] = fmaf(xv[ni].w, wv[3].w, acc[ni][3]);
        }
    }

#pragma unroll
    for (int ni = 0; ni < 4; ++ni) {
        int node = nodeBase + ng * 4 + ni;
        if (node < N) {
            float dn = dinv[node];
            float4 r = make_float4(acc[ni][0] * dn, acc[ni][1] * dn,
                                   acc[ni][2] * dn, acc[ni][3] * dn);
            *(float4*)&out[(size_t)node * NOUT + jg * 4] = r;
        }
    }
}

// ---------------- Pull aggregation: out[n] = relu?(dinv[n]*(h'[n] + sum h'[src]) + b) ----------------

template <int F, bool RELU>
__global__ __launch_bounds__(256) void agg_pull(const float* __restrict__ h,
                                                const float* __restrict__ dinv,
                                                const float* __restrict__ bias,
                                                const int* __restrict__ edge_src,
                                                const int* __restrict__ offsets,
                                                float* __restrict__ out, int N) {
    int lane = threadIdx.x & 63;
    int wave = blockIdx.x * (256 >> 6) + (threadIdx.x >> 6);
    constexpr int GPW = 64 / F;  // node groups per wave
    int node = wave * GPW + lane / F;
    int f = lane % F;
    if (node >= N) return;
    float dn = dinv[node];
    float acc = h[(size_t)node * F + f];  // self-loop (h' already has dinv[n])
    int beg = offsets[node], end = offsets[node + 1];
    int j = beg;
    for (; j + 8 <= end; j += 8) {
        int s[8];
#pragma unroll
        for (int u = 0; u < 8; ++u) s[u] = edge_src[j + u];
        float v[8];
#pragma unroll
        for (int u = 0; u < 8; ++u) v[u] = h[(size_t)s[u] * F + f];
#pragma unroll
        for (int u = 0; u < 8; ++u) acc += v[u];
    }
    for (; j < end; ++j) acc += h[(size_t)edge_src[j] * F + f];
    float r = acc * dn + bias[f];
    if (RELU) r = fmaxf(r, 0.f);
    out[(size_t)node * F + f] = r;
}

// ---------------- Decode: tiled GEMM. link_pred[e] = relu(ef@W1+b1)@w2 + b2 ----------------

#define DTILE 64

__global__ __launch_bounds__(256) void decode_kernel(const float* __restrict__ z,  // [N,32]
                                                     const int* __restrict__ eli, int EL,
                                                     const float* __restrict__ lpW1,
                                                     const float* __restrict__ lpb1,
                                                     const float* __restrict__ lpW2,
                                                     const float* __restrict__ lpb2,
                                                     float* __restrict__ out) {
    __shared__ float Ws[64 * 64];             // W1[k][j]
    __shared__ float efT[64][DTILE + 4];      // [k][e], +4 pad
    __shared__ float red[16][DTILE + 1];      // j-group partials per edge
    for (int i = threadIdx.x; i < 64 * 64; i += 256) Ws[i] = lpW1[i];

    const int t = threadIdx.x;
    const int e0 = t & 15;   // edge block (4 edges)
    const int j0 = t >> 4;   // col block (4 cols)
    float w2r[4], b1r[4];
#pragma unroll
    for (int i = 0; i < 4; ++i) { w2r[i] = lpW2[j0 * 4 + i]; b1r[i] = lpb1[j0 * 4 + i]; }
    const float b2v = lpb2[0];

    const int r = t >> 1;          // row task 0..127
    const int half = t & 1;        // which 64B half of the 128B row
    const int which = r >> 6;      // 0 -> endpoint A, 1 -> endpoint B
    const int eRow = r & 63;

    const int nTiles = EL / DTILE;
    for (int tile = blockIdx.x; tile < nTiles; tile += gridDim.x) {
        int node = eli[which * EL + tile * DTILE + eRow];
        const float4* zp = (const float4*)(z + (size_t)node * 32) + half * 4;
#pragma unroll
        for (int q = 0; q < 4; ++q) {
            float4 v = zp[q];
            int kk = which * 32 + half * 16 + q * 4;
            efT[kk + 0][eRow] = v.x;
            efT[kk + 1][eRow] = v.y;
            efT[kk + 2][eRow] = v.z;
            efT[kk + 3][eRow] = v.w;
        }
        __syncthreads();

        float acc[4][4];
#pragma unroll
        for (int i = 0; i < 4; ++i)
#pragma unroll
            for (int jj = 0; jj < 4; ++jj) acc[i][jj] = 0.f;
#pragma unroll 8
        for (int k = 0; k < 64; ++k) {
            float4 ef = *(const float4*)&efT[k][e0 * 4];
            float4 wv = *(const float4*)&Ws[k * 64 + j0 * 4];
            acc[0][0] = fmaf(ef.x, wv.x, acc[0][0]);
            acc[0][1] = fmaf(ef.x, wv.y, acc[0][1]);
            acc[0][2] = fmaf(ef.x, wv.z, acc[0][2]);
            acc[0][3] = fmaf(ef.x, wv.w, acc[0][3]);
            acc[1][0] = fmaf(ef.y, wv.x, acc[1][0]);
            acc[1][1] = fmaf(ef.y, wv.y, acc[1][1]);
            acc[1][2] = fmaf(ef.y, wv.z, acc[1][2]);
            acc[1][3] = fmaf(ef.y, wv.w, acc[1][3]);
            acc[2][0] = fmaf(ef.z, wv.x, acc[2][0]);
            acc[2][1] = fmaf(ef.z, wv.y, acc[2][1]);
            acc[2][2] = fmaf(ef.z, wv.z, acc[2][2]);
            acc[2][3] = fmaf(ef.z, wv.w, acc[2][3]);
            acc[3][0] = fmaf(ef.w, wv.x, acc[3][0]);
            acc[3][1] = fmaf(ef.w, wv.y, acc[3][1]);
            acc[3][2] = fmaf(ef.w, wv.z, acc[3][2]);
            acc[3][3] = fmaf(ef.w, wv.w, acc[3][3]);
        }

#pragma unroll
        for (int i = 0; i < 4; ++i) {
            float s = 0.f;
#pragma unroll
            for (int jj = 0; jj < 4; ++jj)
                s = fmaf(fmaxf(acc[i][jj] + b1r[jj], 0.f), w2r[jj], s);
            red[j0][e0 * 4 + i] = s;
        }
        __syncthreads();
        if (t < DTILE) {
            float s = 0.f;
#pragma unroll
            for (int g = 0; g < 16; ++g) s += red[g][t];
            out[tile * DTILE + t] = s + b2v;
        }
    }
}

// ---------------- launch ----------------

extern "C" void kernel_launch(void* const* d_in, const int* in_sizes, int n_in,
                              void* d_out, int out_size, void* d_ws, size_t ws_size,
                              hipStream_t stream) {
    const float* x    = (const float*)d_in[0];
    const int* ei     = (const int*)d_in[1];
    const int* eli    = (const int*)d_in[2];
    const float* W1   = (const float*)d_in[3];
    const float* b1   = (const float*)d_in[4];
    const float* W2   = (const float*)d_in[5];
    const float* b2   = (const float*)d_in[6];
    const float* W3   = (const float*)d_in[7];
    const float* b3   = (const float*)d_in[8];
    const float* lpW1 = (const float*)d_in[9];
    const float* lpb1 = (const float*)d_in[10];
    const float* lpW2 = (const float*)d_in[11];
    const float* lpb2 = (const float*)d_in[12];

    const int N  = in_sizes[0] / 128;   // 100000
    const int E  = in_sizes[1] / 2;     // 3200000
    const int EL = in_sizes[2] / 2;     // 1000000

    char* p = (char*)d_ws;
    auto alloc = [&](size_t bytes) { void* r = (void*)p; p += (bytes + 255) & ~(size_t)255; return r; };
    float* dinv     = (float*)alloc((size_t)N * 4);
    int*   offsets  = (int*)alloc((size_t)(N + 1) * 4);
    int*   bcount   = (int*)alloc(1024 * 4);
    int*   bbase    = (int*)alloc(1024 * 4);
    int*   bcur     = (int*)alloc(1024 * 4);
    int*   edge_src = (int*)alloc((size_t)E * 4);
    float* bufG     = (float*)alloc((size_t)N * 64 * 4);
    float* bufZ     = (float*)alloc((size_t)N * 64 * 4);
    int*   pairs    = (int*)bufG;   // alias: pairs lifetime ends before gemm writes bufG

    const int* rowv = ei;        // edge_index[0] = source
    const int* colv = ei + E;    // edge_index[1] = target

    int nbuk = (N + 127) / 128;  // 782
    int nchunk = (E + BINA_CHUNK - 1) / BINA_CHUNK;

    hipMemsetAsync(bcount, 0, (size_t)nbuk * 4, stream);
    bhist_kernel<<<nchunk, 256, 0, stream>>>(colv, bcount, E, nbuk);
    bscan_kernel<<<1, 256, 0, stream>>>(bcount, bbase, bcur, nbuk, offsets, N);
    binA_kernel<<<nchunk, 256, 0, stream>>>(rowv, colv, bcur, pairs, E, nbuk);
    binB_kernel<<<nbuk, 256, 0, stream>>>(pairs, bbase, offsets, dinv, edge_src, N);

    float* zout = (float*)d_out + EL;   // z lives in the output tail (float32)

    int gblocks = (N + 63) / 64;  // 1563

    // layer 1: x[N,128] -> bufG h' -> bufZ (relu)
    gemm_scale<128, 64><<<gblocks, 256, 0, stream>>>(x, W1, dinv, bufG, N);
    agg_pull<64, true><<<(N + 3) / 4, 256, 0, stream>>>(bufG, dinv, b1, edge_src, offsets, bufZ, N);
    // layer 2
    gemm_scale<64, 64><<<gblocks, 256, 0, stream>>>(bufZ, W2, dinv, bufG, N);
    agg_pull<64, true><<<(N + 3) / 4, 256, 0, stream>>>(bufG, dinv, b2, edge_src, offsets, bufZ, N);
    // layer 3: 32-wide, write z directly into d_out tail
    gemm_scale<64, 32><<<gblocks, 128, 0, stream>>>(bufZ, W3, dinv, bufG, N);
    agg_pull<32, false><<<(N + 7) / 8, 256, 0, stream>>>(bufG, dinv, b3, edge_src, offsets, zout, N);
    // decode reads z from d_out tail
    decode_kernel<<<1024, 256, 0, stream>>>(zout, eli, EL, lpW1, lpb1, lpW2, lpb2, (float*)d_out);
}

// Round 8
// 732.609 us; speedup vs baseline: 2.2606x; 1.0134x over previous
//
#include <hip/hip_runtime.h>
#include <hip/hip_bf16.h>

// MusicGNN — 3-layer GCN encoder + MLP link predictor.
// N=100000, F_IN=128, HID=64, OUT=32, E=3.2M edges, EL=1M label edges.
// Inputs: float32 (x, weights, biases), int32 (edge indices).
// Output float32: [link_pred (1M) | z (100000*32)] concatenated flat.
//
// R7: decode was LDS-pipe bound (6144 cyc/tile of ds_read vs 2048 of FMA).
// Replaced per-edge 64x64 GEMM by per-node precompute:
//   u = z@W1[0:32,:], v = z@W1[32:64,:]  (gemm_uv, 25x fewer MACs)
//   link_pred[e] = relu(u[a]+v[b]+b1)·w2 + b2  (decode_edge, gather-bound)
// uv[N][128] aliases the dead bufG+bufZ region.

#define BINA_CHUNK 4096

// ---------------- bucket histogram: bcount[b] += per-block LDS hist ----------------

__global__ __launch_bounds__(256) void bhist_kernel(const int* __restrict__ colv,
                                                    int* __restrict__ bcount,
                                                    int E, int nbuck) {
    __shared__ int hist[800];
    int base = blockIdx.x * BINA_CHUNK;
    int end = min(base + BINA_CHUNK, E);
    for (int i = threadIdx.x; i < nbuck; i += 256) hist[i] = 0;
    __syncthreads();
    for (int e = base + threadIdx.x; e < end; e += 256)
        atomicAdd(&hist[colv[e] >> 7], 1);
    __syncthreads();
    for (int b = threadIdx.x; b < nbuck; b += 256) {
        int c = hist[b];
        if (c > 0) atomicAdd(&bcount[b], c);
    }
}

// ---------------- bucket scan: bbase/bcur = exscan(bcount); offsets[N]=E ----------------

__global__ __launch_bounds__(256) void bscan_kernel(const int* __restrict__ bcount,
                                                    int* __restrict__ bbase,
                                                    int* __restrict__ bcur,
                                                    int nbuck, int* __restrict__ offsets, int N) {
    __shared__ int sh[256];
    int base = threadIdx.x * 4;
    int v[4]; int tsum = 0;
#pragma unroll
    for (int i = 0; i < 4; ++i) { int idx = base + i; v[i] = (idx < nbuck) ? bcount[idx] : 0; tsum += v[i]; }
    sh[threadIdx.x] = tsum;
    __syncthreads();
#pragma unroll
    for (int off = 1; off < 256; off <<= 1) {
        int y = (threadIdx.x >= (unsigned)off) ? sh[threadIdx.x - off] : 0;
        __syncthreads();
        sh[threadIdx.x] += y;
        __syncthreads();
    }
    int ex = sh[threadIdx.x] - tsum;
#pragma unroll
    for (int i = 0; i < 4; ++i) {
        int idx = base + i;
        if (idx < nbuck) { bbase[idx] = ex; bcur[idx] = ex; ex += v[i]; }
        else if (idx == nbuck) { bbase[idx] = ex; offsets[N] = ex; }  // = E
    }
}

// ---------------- Phase A: block-local counting sort into buckets ----------------

__global__ __launch_bounds__(256) void binA_kernel(const int* __restrict__ rowv,
                                                   const int* __restrict__ colv,
                                                   int* __restrict__ bcur,
                                                   int* __restrict__ pairs,
                                                   int E, int nbuck) {
    __shared__ int hist[800];
    __shared__ int pos[800];
    int base = blockIdx.x * BINA_CHUNK;
    int end = min(base + BINA_CHUNK, E);
    for (int i = threadIdx.x; i < nbuck; i += 256) hist[i] = 0;
    __syncthreads();
    for (int e = base + threadIdx.x; e < end; e += 256)
        atomicAdd(&hist[colv[e] >> 7], 1);
    __syncthreads();
    for (int b = threadIdx.x; b < nbuck; b += 256) {
        int c = hist[b];
        pos[b] = (c > 0) ? atomicAdd(&bcur[b], c) : 0;  // reserve contiguous run
    }
    __syncthreads();
    for (int e = base + threadIdx.x; e < end; e += 256) {
        int c = colv[e];
        int g = atomicAdd(&pos[c >> 7], 1);            // LDS cursor
        pairs[g] = (rowv[e] << 7) | (c & 127);          // row<2^17 -> fits
    }
}

// ---------------- Phase B: per bucket — node hist, scan, offsets+dinv, scatter ----------------

__global__ __launch_bounds__(256) void binB_kernel(const int* __restrict__ pairs,
                                                   const int* __restrict__ bbase,
                                                   int* __restrict__ offsets,
                                                   float* __restrict__ dinv,
                                                   int* __restrict__ edge_src, int N) {
    __shared__ int lcnt[128];
    __shared__ int sc[128];
    __shared__ int lcur[128];
    int nodeBeg = blockIdx.x << 7;
    int segBeg = bbase[blockIdx.x];
    int segEnd = bbase[blockIdx.x + 1];
    if (threadIdx.x < 128) lcnt[threadIdx.x] = 0;
    __syncthreads();
    for (int e = segBeg + threadIdx.x; e < segEnd; e += 256)
        atomicAdd(&lcnt[pairs[e] & 127], 1);
    __syncthreads();
    int v = (threadIdx.x < 128) ? lcnt[threadIdx.x] : 0;
    if (threadIdx.x < 128) sc[threadIdx.x] = v;
    __syncthreads();
    for (int off = 1; off < 128; off <<= 1) {
        int y = 0;
        if (threadIdx.x < 128 && threadIdx.x >= (unsigned)off) y = sc[threadIdx.x - off];
        __syncthreads();
        if (threadIdx.x < 128) sc[threadIdx.x] += y;
        __syncthreads();
    }
    if (threadIdx.x < 128) {
        int ex = sc[threadIdx.x] - v;
        lcur[threadIdx.x] = ex;
        int node = nodeBeg + threadIdx.x;
        if (node < N) {
            offsets[node] = segBeg + ex;              // coalesced
            dinv[node] = rsqrtf((float)(v + 1));      // +1: self loop
        }
    }
    __syncthreads();
    for (int e = segBeg + threadIdx.x; e < segEnd; e += 256) {
        int p = pairs[e];
        int rel = atomicAdd(&lcur[p & 127], 1);
        edge_src[segBeg + rel] = p >> 7;
    }
}

// ---------------- GEMM + dinv scale: h'[n][j] = dinv[n] * sum_k in[n][k]*W[k][j] ----------------

template <int K, int NOUT>
__global__ __launch_bounds__(16 * (NOUT / 4)) void gemm_scale(const float* __restrict__ in_,
                                                              const float* __restrict__ W,
                                                              const float* __restrict__ dinv,
                                                              float* __restrict__ out, int N) {
    constexpr int TPB = 16 * (NOUT / 4);
    constexpr int XPITCH = K + 4;
    __shared__ float xs[64 * XPITCH];
    __shared__ float ws[K * NOUT];

    const int tid = threadIdx.x;
    const int nodeBase = blockIdx.x * 64;

    for (int i = tid; i < K * NOUT / 4; i += TPB)
        *(float4*)&ws[i * 4] = *(const float4*)&W[i * 4];
    for (int i = tid; i < 64 * K / 4; i += TPB) {
        int row = i / (K / 4), c = i % (K / 4);
        int src = nodeBase + row; if (src >= N) src = N - 1;
        *(float4*)&xs[row * XPITCH + c * 4] = *(const float4*)&in_[(size_t)src * K + c * 4];
    }
    __syncthreads();

    const int jg = tid % (NOUT / 4);
    const int ng = tid / (NOUT / 4);

    float acc[4][4];
#pragma unroll
    for (int i = 0; i < 4; ++i)
#pragma unroll
        for (int j = 0; j < 4; ++j) acc[i][j] = 0.f;

    for (int kc = 0; kc < K / 4; ++kc) {
        float4 xv[4], wv[4];
#pragma unroll
        for (int ni = 0; ni < 4; ++ni)
            xv[ni] = *(const float4*)&xs[(ng * 4 + ni) * XPITCH + kc * 4];
#pragma unroll
        for (int t = 0; t < 4; ++t)
            wv[t] = *(const float4*)&ws[(kc * 4 + t) * NOUT + jg * 4];
#pragma unroll
        for (int ni = 0; ni < 4; ++ni) {
            acc[ni][0] = fmaf(xv[ni].x, wv[0].x, acc[ni][0]);
            acc[ni][1] = fmaf(xv[ni].x, wv[0].y, acc[ni][1]);
            acc[ni][2] = fmaf(xv[ni].x, wv[0].z, acc[ni][2]);
            acc[ni][3] = fmaf(xv[ni].x, wv[0].w, acc[ni][3]);
            acc[ni][0] = fmaf(xv[ni].y, wv[1].x, acc[ni][0]);
            acc[ni][1] = fmaf(xv[ni].y, wv[1].y, acc[ni][1]);
            acc[ni][2] = fmaf(xv[ni].y, wv[1].z, acc[ni][2]);
            acc[ni][3] = fmaf(xv[ni].y, wv[1].w, acc[ni][3]);
            acc[ni][0] = fmaf(xv[ni].z, wv[2].x, acc[ni][0]);
            acc[ni][1] = fmaf(xv[ni].z, wv[2].y, acc[ni][1]);
            acc[ni][2] = fmaf(xv[ni].z, wv[2].z, acc[ni][2]);
            acc[ni][3] = fmaf(xv[ni].z, wv[2].w, acc[ni][3]);
            acc[ni][0] = fmaf(xv[ni].w, wv[3].x, acc[ni][0]);
            acc[ni][1] = fmaf(xv[ni].w, wv[3].y, acc[ni][1]);
            acc[ni][2] = fmaf(xv[ni].w, wv[3].z, acc[ni][2]);
            acc[ni][3] = fmaf(xv[ni].w, wv[3].w, acc[ni][3]);
        }
    }

#pragma unroll
    for (int ni = 0; ni < 4; ++ni) {
        int node = nodeBase + ng * 4 + ni;
        if (node < N) {
            float dn = dinv[node];
            float4 r = make_float4(acc[ni][0] * dn, acc[ni][1] * dn,
                                   acc[ni][2] * dn, acc[ni][3] * dn);
            *(float4*)&out[(size_t)node * NOUT + jg * 4] = r;
        }
    }
}

// ---------------- Pull aggregation: out[n] = relu?(dinv[n]*(h'[n] + sum h'[src]) + b) ----------------

template <int F, bool RELU>
__global__ __launch_bounds__(256) void agg_pull(const float* __restrict__ h,
                                                const float* __restrict__ dinv,
                                                const float* __restrict__ bias,
                                                const int* __restrict__ edge_src,
                                                const int* __restrict__ offsets,
                                                float* __restrict__ out, int N) {
    int lane = threadIdx.x & 63;
    int wave = blockIdx.x * (256 >> 6) + (threadIdx.x >> 6);
    constexpr int GPW = 64 / F;
    int node = wave * GPW + lane / F;
    int f = lane % F;
    if (node >= N) return;
    float dn = dinv[node];
    float acc = h[(size_t)node * F + f];
    int beg = offsets[node], end = offsets[node + 1];
    int j = beg;
    for (; j + 8 <= end; j += 8) {
        int s[8];
#pragma unroll
        for (int u = 0; u < 8; ++u) s[u] = edge_src[j + u];
        float v[8];
#pragma unroll
        for (int u = 0; u < 8; ++u) v[u] = h[(size_t)s[u] * F + f];
#pragma unroll
        for (int u = 0; u < 8; ++u) acc += v[u];
    }
    for (; j < end; ++j) acc += h[(size_t)edge_src[j] * F + f];
    float r = acc * dn + bias[f];
    if (RELU) r = fmaxf(r, 0.f);
    out[(size_t)node * F + f] = r;
}

// ---------------- Decode stage 1: uv[n] = [z[n]@W1_top | z[n]@W1_bot] ----------------
// 64-node tile, per-thread 4 nodes x 4 cols, BOTH u and v accumulators.

__global__ __launch_bounds__(256) void gemm_uv(const float* __restrict__ z,   // [N,32]
                                               const float* __restrict__ W1,  // [64,64]
                                               float* __restrict__ uv, int N) {
    constexpr int ZPITCH = 36;
    __shared__ float zs[64 * ZPITCH];
    __shared__ float ws[64 * 64];
    const int tid = threadIdx.x;
    const int nodeBase = blockIdx.x * 64;

    for (int i = tid; i < 64 * 64 / 4; i += 256)
        *(float4*)&ws[i * 4] = *(const float4*)&W1[i * 4];
    for (int i = tid; i < 64 * 8; i += 256) {   // 64 rows x 8 float4
        int row = i / 8, c = i % 8;
        int src = nodeBase + row; if (src >= N) src = N - 1;
        *(float4*)&zs[row * ZPITCH + c * 4] = *(const float4*)&z[(size_t)src * 32 + c * 4];
    }
    __syncthreads();

    const int jg = tid % 16;
    const int ng = tid / 16;

    float au[4][4], av[4][4];
#pragma unroll
    for (int i = 0; i < 4; ++i)
#pragma unroll
        for (int j = 0; j < 4; ++j) { au[i][j] = 0.f; av[i][j] = 0.f; }

    for (int kc = 0; kc < 8; ++kc) {            // K = 32
        float4 xv[4], wu[4], wv2[4];
#pragma unroll
        for (int ni = 0; ni < 4; ++ni)
            xv[ni] = *(const float4*)&zs[(ng * 4 + ni) * ZPITCH + kc * 4];
#pragma unroll
        for (int t = 0; t < 4; ++t) {
            wu[t]  = *(const float4*)&ws[(kc * 4 + t) * 64 + jg * 4];
            wv2[t] = *(const float4*)&ws[(32 + kc * 4 + t) * 64 + jg * 4];
        }
#pragma unroll
        for (int ni = 0; ni < 4; ++ni) {
            float xk[4] = {xv[ni].x, xv[ni].y, xv[ni].z, xv[ni].w};
#pragma unroll
            for (int t = 0; t < 4; ++t) {
                au[ni][0] = fmaf(xk[t], wu[t].x, au[ni][0]);
                au[ni][1] = fmaf(xk[t], wu[t].y, au[ni][1]);
                au[ni][2] = fmaf(xk[t], wu[t].z, au[ni][2]);
                au[ni][3] = fmaf(xk[t], wu[t].w, au[ni][3]);
                av[ni][0] = fmaf(xk[t], wv2[t].x, av[ni][0]);
                av[ni][1] = fmaf(xk[t], wv2[t].y, av[ni][1]);
                av[ni][2] = fmaf(xk[t], wv2[t].z, av[ni][2]);
                av[ni][3] = fmaf(xk[t], wv2[t].w, av[ni][3]);
            }
        }
    }

#pragma unroll
    for (int ni = 0; ni < 4; ++ni) {
        int node = nodeBase + ng * 4 + ni;
        if (node < N) {
            *(float4*)&uv[(size_t)node * 128 + jg * 4]      = make_float4(au[ni][0], au[ni][1], au[ni][2], au[ni][3]);
            *(float4*)&uv[(size_t)node * 128 + 64 + jg * 4] = make_float4(av[ni][0], av[ni][1], av[ni][2], av[ni][3]);
        }
    }
}

// ---------------- Decode stage 2: link_pred[e] = relu(u[a]+v[b]+b1)·w2 + b2 ----------------
// 16 lanes per edge; 256B contiguous gathers; segmented shfl reduce.

__global__ __launch_bounds__(256) void decode_edge(const float* __restrict__ uv,
                                                   const int* __restrict__ eli, int EL,
                                                   const float* __restrict__ lpb1,
                                                   const float* __restrict__ lpW2,
                                                   const float* __restrict__ lpb2,
                                                   float* __restrict__ out) {
    const int sub = threadIdx.x & 15;
    float4 b1r = *(const float4*)&lpb1[sub * 4];
    float4 w2r = *(const float4*)&lpW2[sub * 4];
    const float b2v = lpb2[0];
    int e = blockIdx.x * 16 + (threadIdx.x >> 4);
    if (e >= EL) return;
    int a = eli[e], b = eli[EL + e];
    float4 ua = *(const float4*)&uv[(size_t)a * 128 + sub * 4];
    float4 vb = *(const float4*)&uv[(size_t)b * 128 + 64 + sub * 4];
    float p = fmaxf(ua.x + vb.x + b1r.x, 0.f) * w2r.x;
    p = fmaf(fmaxf(ua.y + vb.y + b1r.y, 0.f), w2r.y, p);
    p = fmaf(fmaxf(ua.z + vb.z + b1r.z, 0.f), w2r.z, p);
    p = fmaf(fmaxf(ua.w + vb.w + b1r.w, 0.f), w2r.w, p);
    p += __shfl_down(p, 8, 16);
    p += __shfl_down(p, 4, 16);
    p += __shfl_down(p, 2, 16);
    p += __shfl_down(p, 1, 16);
    if (sub == 0) out[e] = p + b2v;
}

// ---------------- launch ----------------

extern "C" void kernel_launch(void* const* d_in, const int* in_sizes, int n_in,
                              void* d_out, int out_size, void* d_ws, size_t ws_size,
                              hipStream_t stream) {
    const float* x    = (const float*)d_in[0];
    const int* ei     = (const int*)d_in[1];
    const int* eli    = (const int*)d_in[2];
    const float* W1   = (const float*)d_in[3];
    const float* b1   = (const float*)d_in[4];
    const float* W2   = (const float*)d_in[5];
    const float* b2   = (const float*)d_in[6];
    const float* W3   = (const float*)d_in[7];
    const float* b3   = (const float*)d_in[8];
    const float* lpW1 = (const float*)d_in[9];
    const float* lpb1 = (const float*)d_in[10];
    const float* lpW2 = (const float*)d_in[11];
    const float* lpb2 = (const float*)d_in[12];

    const int N  = in_sizes[0] / 128;   // 100000
    const int E  = in_sizes[1] / 2;     // 3200000
    const int EL = in_sizes[2] / 2;     // 1000000

    char* p = (char*)d_ws;
    auto alloc = [&](size_t bytes) { void* r = (void*)p; p += (bytes + 255) & ~(size_t)255; return r; };
    float* dinv     = (float*)alloc((size_t)N * 4);
    int*   offsets  = (int*)alloc((size_t)(N + 1) * 4);
    int*   bcount   = (int*)alloc(1024 * 4);
    int*   bbase    = (int*)alloc(1024 * 4);
    int*   bcur     = (int*)alloc(1024 * 4);
    int*   edge_src = (int*)alloc((size_t)E * 4);
    float* bufG     = (float*)alloc((size_t)N * 64 * 4);
    float* bufZ     = (float*)alloc((size_t)N * 64 * 4);
    int*   pairs    = (int*)bufG;   // alias: dead before gemm writes bufG
    float* uvbuf    = bufG;         // alias: bufG+bufZ contiguous 51.2MB, dead after layer 3

    const int* rowv = ei;        // edge_index[0] = source
    const int* colv = ei + E;    // edge_index[1] = target

    int nbuk = (N + 127) / 128;  // 782
    int nchunk = (E + BINA_CHUNK - 1) / BINA_CHUNK;

    hipMemsetAsync(bcount, 0, (size_t)nbuk * 4, stream);
    bhist_kernel<<<nchunk, 256, 0, stream>>>(colv, bcount, E, nbuk);
    bscan_kernel<<<1, 256, 0, stream>>>(bcount, bbase, bcur, nbuk, offsets, N);
    binA_kernel<<<nchunk, 256, 0, stream>>>(rowv, colv, bcur, pairs, E, nbuk);
    binB_kernel<<<nbuk, 256, 0, stream>>>(pairs, bbase, offsets, dinv, edge_src, N);

    float* zout = (float*)d_out + EL;   // z lives in the output tail (float32)

    int gblocks = (N + 63) / 64;  // 1563

    // layer 1: x[N,128] -> bufG h' -> bufZ (relu)
    gemm_scale<128, 64><<<gblocks, 256, 0, stream>>>(x, W1, dinv, bufG, N);
    agg_pull<64, true><<<(N + 3) / 4, 256, 0, stream>>>(bufG, dinv, b1, edge_src, offsets, bufZ, N);
    // layer 2
    gemm_scale<64, 64><<<gblocks, 256, 0, stream>>>(bufZ, W2, dinv, bufG, N);
    agg_pull<64, true><<<(N + 3) / 4, 256, 0, stream>>>(bufG, dinv, b2, edge_src, offsets, bufZ, N);
    // layer 3: 32-wide, write z directly into d_out tail
    gemm_scale<64, 32><<<gblocks, 128, 0, stream>>>(bufZ, W3, dinv, bufG, N);
    agg_pull<32, false><<<(N + 7) / 8, 256, 0, stream>>>(bufG, dinv, b3, edge_src, offsets, zout, N);
    // decode: per-node uv precompute, then per-edge gather+epilogue
    gemm_uv<<<gblocks, 256, 0, stream>>>(zout, lpW1, uvbuf, N);
    decode_edge<<<(EL + 15) / 16, 256, 0, stream>>>(uvbuf, eli, EL, lpb1, lpW2, lpb2, (float*)d_out);
}

// Round 9
// 679.477 us; speedup vs baseline: 2.4374x; 1.0782x over previous
//
#include <hip/hip_runtime.h>
#include <hip/hip_bf16.h>
#include <hip/hip_fp16.h>

// MusicGNN — 3-layer GCN encoder + MLP link predictor.
// N=100000, F_IN=128, HID=64, OUT=32, E=3.2M edges, EL=1M label edges.
// Inputs: float32 (x, weights, biases), int32 (edge indices).
// Output float32: [link_pred (1M) | z (100000*32)] concatenated flat.
//
// R8: agg_pull was LLC-BW bound (362MB HBM-side fetch per dispatch; 819MB
// logical row-gather traffic). Message buffers h' and uv are now fp16
// (fp32 accumulation everywhere): halves gather bytes + line count.
// fp16 not bf16: 2^-12 rel err keeps absmax well under threshold.

#define BINA_CHUNK 4096

// ---------------- bucket histogram ----------------

__global__ __launch_bounds__(256) void bhist_kernel(const int* __restrict__ colv,
                                                    int* __restrict__ bcount,
                                                    int E, int nbuck) {
    __shared__ int hist[800];
    int base = blockIdx.x * BINA_CHUNK;
    int end = min(base + BINA_CHUNK, E);
    for (int i = threadIdx.x; i < nbuck; i += 256) hist[i] = 0;
    __syncthreads();
    for (int e = base + threadIdx.x; e < end; e += 256)
        atomicAdd(&hist[colv[e] >> 7], 1);
    __syncthreads();
    for (int b = threadIdx.x; b < nbuck; b += 256) {
        int c = hist[b];
        if (c > 0) atomicAdd(&bcount[b], c);
    }
}

// ---------------- bucket scan ----------------

__global__ __launch_bounds__(256) void bscan_kernel(const int* __restrict__ bcount,
                                                    int* __restrict__ bbase,
                                                    int* __restrict__ bcur,
                                                    int nbuck, int* __restrict__ offsets, int N) {
    __shared__ int sh[256];
    int base = threadIdx.x * 4;
    int v[4]; int tsum = 0;
#pragma unroll
    for (int i = 0; i < 4; ++i) { int idx = base + i; v[i] = (idx < nbuck) ? bcount[idx] : 0; tsum += v[i]; }
    sh[threadIdx.x] = tsum;
    __syncthreads();
#pragma unroll
    for (int off = 1; off < 256; off <<= 1) {
        int y = (threadIdx.x >= (unsigned)off) ? sh[threadIdx.x - off] : 0;
        __syncthreads();
        sh[threadIdx.x] += y;
        __syncthreads();
    }
    int ex = sh[threadIdx.x] - tsum;
#pragma unroll
    for (int i = 0; i < 4; ++i) {
        int idx = base + i;
        if (idx < nbuck) { bbase[idx] = ex; bcur[idx] = ex; ex += v[i]; }
        else if (idx == nbuck) { bbase[idx] = ex; offsets[N] = ex; }  // = E
    }
}

// ---------------- Phase A: block-local counting sort into buckets ----------------

__global__ __launch_bounds__(256) void binA_kernel(const int* __restrict__ rowv,
                                                   const int* __restrict__ colv,
                                                   int* __restrict__ bcur,
                                                   int* __restrict__ pairs,
                                                   int E, int nbuck) {
    __shared__ int hist[800];
    __shared__ int pos[800];
    int base = blockIdx.x * BINA_CHUNK;
    int end = min(base + BINA_CHUNK, E);
    for (int i = threadIdx.x; i < nbuck; i += 256) hist[i] = 0;
    __syncthreads();
    for (int e = base + threadIdx.x; e < end; e += 256)
        atomicAdd(&hist[colv[e] >> 7], 1);
    __syncthreads();
    for (int b = threadIdx.x; b < nbuck; b += 256) {
        int c = hist[b];
        pos[b] = (c > 0) ? atomicAdd(&bcur[b], c) : 0;
    }
    __syncthreads();
    for (int e = base + threadIdx.x; e < end; e += 256) {
        int c = colv[e];
        int g = atomicAdd(&pos[c >> 7], 1);
        pairs[g] = (rowv[e] << 7) | (c & 127);
    }
}

// ---------------- Phase B: per bucket — node hist, scan, offsets+dinv, scatter ----------------

__global__ __launch_bounds__(256) void binB_kernel(const int* __restrict__ pairs,
                                                   const int* __restrict__ bbase,
                                                   int* __restrict__ offsets,
                                                   float* __restrict__ dinv,
                                                   int* __restrict__ edge_src, int N) {
    __shared__ int lcnt[128];
    __shared__ int sc[128];
    __shared__ int lcur[128];
    int nodeBeg = blockIdx.x << 7;
    int segBeg = bbase[blockIdx.x];
    int segEnd = bbase[blockIdx.x + 1];
    if (threadIdx.x < 128) lcnt[threadIdx.x] = 0;
    __syncthreads();
    for (int e = segBeg + threadIdx.x; e < segEnd; e += 256)
        atomicAdd(&lcnt[pairs[e] & 127], 1);
    __syncthreads();
    int v = (threadIdx.x < 128) ? lcnt[threadIdx.x] : 0;
    if (threadIdx.x < 128) sc[threadIdx.x] = v;
    __syncthreads();
    for (int off = 1; off < 128; off <<= 1) {
        int y = 0;
        if (threadIdx.x < 128 && threadIdx.x >= (unsigned)off) y = sc[threadIdx.x - off];
        __syncthreads();
        if (threadIdx.x < 128) sc[threadIdx.x] += y;
        __syncthreads();
    }
    if (threadIdx.x < 128) {
        int ex = sc[threadIdx.x] - v;
        lcur[threadIdx.x] = ex;
        int node = nodeBeg + threadIdx.x;
        if (node < N) {
            offsets[node] = segBeg + ex;
            dinv[node] = rsqrtf((float)(v + 1));
        }
    }
    __syncthreads();
    for (int e = segBeg + threadIdx.x; e < segEnd; e += 256) {
        int p = pairs[e];
        int rel = atomicAdd(&lcur[p & 127], 1);
        edge_src[segBeg + rel] = p >> 7;
    }
}

// ---------------- GEMM + dinv scale, fp16 out: h'[n][j] = dinv[n]*sum_k in[n][k]*W[k][j] ----------------

template <int K, int NOUT>
__global__ __launch_bounds__(16 * (NOUT / 4)) void gemm_scale(const float* __restrict__ in_,
                                                              const float* __restrict__ W,
                                                              const float* __restrict__ dinv,
                                                              __half* __restrict__ out, int N) {
    constexpr int TPB = 16 * (NOUT / 4);
    constexpr int XPITCH = K + 4;
    __shared__ float xs[64 * XPITCH];
    __shared__ float ws[K * NOUT];

    const int tid = threadIdx.x;
    const int nodeBase = blockIdx.x * 64;

    for (int i = tid; i < K * NOUT / 4; i += TPB)
        *(float4*)&ws[i * 4] = *(const float4*)&W[i * 4];
    for (int i = tid; i < 64 * K / 4; i += TPB) {
        int row = i / (K / 4), c = i % (K / 4);
        int src = nodeBase + row; if (src >= N) src = N - 1;
        *(float4*)&xs[row * XPITCH + c * 4] = *(const float4*)&in_[(size_t)src * K + c * 4];
    }
    __syncthreads();

    const int jg = tid % (NOUT / 4);
    const int ng = tid / (NOUT / 4);

    float acc[4][4];
#pragma unroll
    for (int i = 0; i < 4; ++i)
#pragma unroll
        for (int j = 0; j < 4; ++j) acc[i][j] = 0.f;

    for (int kc = 0; kc < K / 4; ++kc) {
        float4 xv[4], wv[4];
#pragma unroll
        for (int ni = 0; ni < 4; ++ni)
            xv[ni] = *(const float4*)&xs[(ng * 4 + ni) * XPITCH + kc * 4];
#pragma unroll
        for (int t = 0; t < 4; ++t)
            wv[t] = *(const float4*)&ws[(kc * 4 + t) * NOUT + jg * 4];
#pragma unroll
        for (int ni = 0; ni < 4; ++ni) {
            acc[ni][0] = fmaf(xv[ni].x, wv[0].x, acc[ni][0]);
            acc[ni][1] = fmaf(xv[ni].x, wv[0].y, acc[ni][1]);
            acc[ni][2] = fmaf(xv[ni].x, wv[0].z, acc[ni][2]);
            acc[ni][3] = fmaf(xv[ni].x, wv[0].w, acc[ni][3]);
            acc[ni][0] = fmaf(xv[ni].y, wv[1].x, acc[ni][0]);
            acc[ni][1] = fmaf(xv[ni].y, wv[1].y, acc[ni][1]);
            acc[ni][2] = fmaf(xv[ni].y, wv[1].z, acc[ni][2]);
            acc[ni][3] = fmaf(xv[ni].y, wv[1].w, acc[ni][3]);
            acc[ni][0] = fmaf(xv[ni].z, wv[2].x, acc[ni][0]);
            acc[ni][1] = fmaf(xv[ni].z, wv[2].y, acc[ni][1]);
            acc[ni][2] = fmaf(xv[ni].z, wv[2].z, acc[ni][2]);
            acc[ni][3] = fmaf(xv[ni].z, wv[2].w, acc[ni][3]);
            acc[ni][0] = fmaf(xv[ni].w, wv[3].x, acc[ni][0]);
            acc[ni][1] = fmaf(xv[ni].w, wv[3].y, acc[ni][1]);
            acc[ni][2] = fmaf(xv[ni].w, wv[3].z, acc[ni][2]);
            acc[ni][3] = fmaf(xv[ni].w, wv[3].w, acc[ni][3]);
        }
    }

#pragma unroll
    for (int ni = 0; ni < 4; ++ni) {
        int node = nodeBase + ng * 4 + ni;
        if (node < N) {
            float dn = dinv[node];
            __half2* op = (__half2*)(out + (size_t)node * NOUT + jg * 4);
            op[0] = __floats2half2_rn(acc[ni][0] * dn, acc[ni][1] * dn);
            op[1] = __floats2half2_rn(acc[ni][2] * dn, acc[ni][3] * dn);
        }
    }
}

// ---------------- Pull aggregation (fp16 rows, fp32 accumulate) ----------------

template <int F, bool RELU>
__global__ __launch_bounds__(256) void agg_pull(const __half* __restrict__ h,
                                                const float* __restrict__ dinv,
                                                const float* __restrict__ bias,
                                                const int* __restrict__ edge_src,
                                                const int* __restrict__ offsets,
                                                float* __restrict__ out, int N) {
    int lane = threadIdx.x & 63;
    int wave = blockIdx.x * (256 >> 6) + (threadIdx.x >> 6);
    constexpr int GPW = 64 / F;
    int node = wave * GPW + lane / F;
    int f = lane % F;
    if (node >= N) return;
    float dn = dinv[node];
    float acc = __half2float(h[(size_t)node * F + f]);  // self-loop
    int beg = offsets[node], end = offsets[node + 1];
    int j = beg;
    for (; j + 8 <= end; j += 8) {
        int s[8];
#pragma unroll
        for (int u = 0; u < 8; ++u) s[u] = edge_src[j + u];
        float v[8];
#pragma unroll
        for (int u = 0; u < 8; ++u) v[u] = __half2float(h[(size_t)s[u] * F + f]);
#pragma unroll
        for (int u = 0; u < 8; ++u) acc += v[u];
    }
    for (; j < end; ++j) acc += __half2float(h[(size_t)edge_src[j] * F + f]);
    float r = acc * dn + bias[f];
    if (RELU) r = fmaxf(r, 0.f);
    out[(size_t)node * F + f] = r;
}

// ---------------- Decode stage 1: uv[n] = [z@W1_top | z@W1_bot] (fp16 out) ----------------

__global__ __launch_bounds__(256) void gemm_uv(const float* __restrict__ z,   // [N,32]
                                               const float* __restrict__ W1,  // [64,64]
                                               __half* __restrict__ uv, int N) {
    constexpr int ZPITCH = 36;
    __shared__ float zs[64 * ZPITCH];
    __shared__ float ws[64 * 64];
    const int tid = threadIdx.x;
    const int nodeBase = blockIdx.x * 64;

    for (int i = tid; i < 64 * 64 / 4; i += 256)
        *(float4*)&ws[i * 4] = *(const float4*)&W1[i * 4];
    for (int i = tid; i < 64 * 8; i += 256) {
        int row = i / 8, c = i % 8;
        int src = nodeBase + row; if (src >= N) src = N - 1;
        *(float4*)&zs[row * ZPITCH + c * 4] = *(const float4*)&z[(size_t)src * 32 + c * 4];
    }
    __syncthreads();

    const int jg = tid % 16;
    const int ng = tid / 16;

    float au[4][4], av[4][4];
#pragma unroll
    for (int i = 0; i < 4; ++i)
#pragma unroll
        for (int j = 0; j < 4; ++j) { au[i][j] = 0.f; av[i][j] = 0.f; }

    for (int kc = 0; kc < 8; ++kc) {            // K = 32
        float4 xv[4], wu[4], wv2[4];
#pragma unroll
        for (int ni = 0; ni < 4; ++ni)
            xv[ni] = *(const float4*)&zs[(ng * 4 + ni) * ZPITCH + kc * 4];
#pragma unroll
        for (int t = 0; t < 4; ++t) {
            wu[t]  = *(const float4*)&ws[(kc * 4 + t) * 64 + jg * 4];
            wv2[t] = *(const float4*)&ws[(32 + kc * 4 + t) * 64 + jg * 4];
        }
#pragma unroll
        for (int ni = 0; ni < 4; ++ni) {
            float xk[4] = {xv[ni].x, xv[ni].y, xv[ni].z, xv[ni].w};
#pragma unroll
            for (int t = 0; t < 4; ++t) {
                au[ni][0] = fmaf(xk[t], wu[t].x, au[ni][0]);
                au[ni][1] = fmaf(xk[t], wu[t].y, au[ni][1]);
                au[ni][2] = fmaf(xk[t], wu[t].z, au[ni][2]);
                au[ni][3] = fmaf(xk[t], wu[t].w, au[ni][3]);
                av[ni][0] = fmaf(xk[t], wv2[t].x, av[ni][0]);
                av[ni][1] = fmaf(xk[t], wv2[t].y, av[ni][1]);
                av[ni][2] = fmaf(xk[t], wv2[t].z, av[ni][2]);
                av[ni][3] = fmaf(xk[t], wv2[t].w, av[ni][3]);
            }
        }
    }

#pragma unroll
    for (int ni = 0; ni < 4; ++ni) {
        int node = nodeBase + ng * 4 + ni;
        if (node < N) {
            __half2* pu = (__half2*)(uv + (size_t)node * 128 + jg * 4);
            pu[0] = __floats2half2_rn(au[ni][0], au[ni][1]);
            pu[1] = __floats2half2_rn(au[ni][2], au[ni][3]);
            __half2* pv = (__half2*)(uv + (size_t)node * 128 + 64 + jg * 4);
            pv[0] = __floats2half2_rn(av[ni][0], av[ni][1]);
            pv[1] = __floats2half2_rn(av[ni][2], av[ni][3]);
        }
    }
}

// ---------------- Decode stage 2: link_pred[e] = relu(u[a]+v[b]+b1)·w2 + b2 ----------------

__global__ __launch_bounds__(256) void decode_edge(const __half* __restrict__ uv,
                                                   const int* __restrict__ eli, int EL,
                                                   const float* __restrict__ lpb1,
                                                   const float* __restrict__ lpW2,
                                                   const float* __restrict__ lpb2,
                                                   float* __restrict__ out) {
    const int sub = threadIdx.x & 15;
    float4 b1r = *(const float4*)&lpb1[sub * 4];
    float4 w2r = *(const float4*)&lpW2[sub * 4];
    const float b2v = lpb2[0];
    int e = blockIdx.x * 16 + (threadIdx.x >> 4);
    if (e >= EL) return;
    int a = eli[e], b = eli[EL + e];
    const __half2* pa = (const __half2*)(uv + (size_t)a * 128 + sub * 4);
    const __half2* pb = (const __half2*)(uv + (size_t)b * 128 + 64 + sub * 4);
    float2 a01 = __half22float2(pa[0]), a23 = __half22float2(pa[1]);
    float2 b01 = __half22float2(pb[0]), b23 = __half22float2(pb[1]);
    float p = fmaxf(a01.x + b01.x + b1r.x, 0.f) * w2r.x;
    p = fmaf(fmaxf(a01.y + b01.y + b1r.y, 0.f), w2r.y, p);
    p = fmaf(fmaxf(a23.x + b23.x + b1r.z, 0.f), w2r.z, p);
    p = fmaf(fmaxf(a23.y + b23.y + b1r.w, 0.f), w2r.w, p);
    p += __shfl_down(p, 8, 16);
    p += __shfl_down(p, 4, 16);
    p += __shfl_down(p, 2, 16);
    p += __shfl_down(p, 1, 16);
    if (sub == 0) out[e] = p + b2v;
}

// ---------------- launch ----------------

extern "C" void kernel_launch(void* const* d_in, const int* in_sizes, int n_in,
                              void* d_out, int out_size, void* d_ws, size_t ws_size,
                              hipStream_t stream) {
    const float* x    = (const float*)d_in[0];
    const int* ei     = (const int*)d_in[1];
    const int* eli    = (const int*)d_in[2];
    const float* W1   = (const float*)d_in[3];
    const float* b1   = (const float*)d_in[4];
    const float* W2   = (const float*)d_in[5];
    const float* b2   = (const float*)d_in[6];
    const float* W3   = (const float*)d_in[7];
    const float* b3   = (const float*)d_in[8];
    const float* lpW1 = (const float*)d_in[9];
    const float* lpb1 = (const float*)d_in[10];
    const float* lpW2 = (const float*)d_in[11];
    const float* lpb2 = (const float*)d_in[12];

    const int N  = in_sizes[0] / 128;   // 100000
    const int E  = in_sizes[1] / 2;     // 3200000
    const int EL = in_sizes[2] / 2;     // 1000000

    char* p = (char*)d_ws;
    auto alloc = [&](size_t bytes) { void* r = (void*)p; p += (bytes + 255) & ~(size_t)255; return r; };
    float* dinv     = (float*)alloc((size_t)N * 4);
    int*   offsets  = (int*)alloc((size_t)(N + 1) * 4);
    int*   bcount   = (int*)alloc(1024 * 4);
    int*   bbase    = (int*)alloc(1024 * 4);
    int*   bcur     = (int*)alloc(1024 * 4);
    int*   edge_src = (int*)alloc((size_t)E * 4);
    __half* bufG    = (__half*)alloc((size_t)N * 64 * 2);   // fp16 messages h'
    float* bufZ     = (float*)alloc((size_t)N * 64 * 4);    // fp32 z1/z2
    __half* uvbuf   = (__half*)alloc((size_t)N * 128 * 2);  // fp16 uv
    int*   pairs    = (int*)uvbuf;  // alias: pairs (12.8MB) dead before gemm_uv writes uv

    const int* rowv = ei;        // edge_index[0] = source
    const int* colv = ei + E;    // edge_index[1] = target

    int nbuk = (N + 127) / 128;  // 782
    int nchunk = (E + BINA_CHUNK - 1) / BINA_CHUNK;

    hipMemsetAsync(bcount, 0, (size_t)nbuk * 4, stream);
    bhist_kernel<<<nchunk, 256, 0, stream>>>(colv, bcount, E, nbuk);
    bscan_kernel<<<1, 256, 0, stream>>>(bcount, bbase, bcur, nbuk, offsets, N);
    binA_kernel<<<nchunk, 256, 0, stream>>>(rowv, colv, bcur, pairs, E, nbuk);
    binB_kernel<<<nbuk, 256, 0, stream>>>(pairs, bbase, offsets, dinv, edge_src, N);

    float* zout = (float*)d_out + EL;   // z lives in the output tail (float32)

    int gblocks = (N + 63) / 64;  // 1563

    // layer 1: x[N,128] -> bufG h' (fp16) -> bufZ (fp32, relu)
    gemm_scale<128, 64><<<gblocks, 256, 0, stream>>>(x, W1, dinv, bufG, N);
    agg_pull<64, true><<<(N + 3) / 4, 256, 0, stream>>>(bufG, dinv, b1, edge_src, offsets, bufZ, N);
    // layer 2
    gemm_scale<64, 64><<<gblocks, 256, 0, stream>>>(bufZ, W2, dinv, bufG, N);
    agg_pull<64, true><<<(N + 3) / 4, 256, 0, stream>>>(bufG, dinv, b2, edge_src, offsets, bufZ, N);
    // layer 3: 32-wide, write z directly into d_out tail
    gemm_scale<64, 32><<<gblocks, 128, 0, stream>>>(bufZ, W3, dinv, bufG, N);
    agg_pull<32, false><<<(N + 7) / 8, 256, 0, stream>>>(bufG, dinv, b3, edge_src, offsets, zout, N);
    // decode: per-node uv precompute (fp16), then per-edge gather+epilogue
    gemm_uv<<<gblocks, 256, 0, stream>>>(zout, lpW1, uvbuf, N);
    decode_edge<<<(EL + 15) / 16, 256, 0, stream>>>(uvbuf, eli, EL, lpb1, lpW2, lpb2, (float*)d_out);
}

// Round 10
// 613.095 us; speedup vs baseline: 2.7013x; 1.1083x over previous
//
#include <hip/hip_runtime.h>
#include <hip/hip_bf16.h>
#include <hip/hip_fp16.h>

// MusicGNN — 3-layer GCN encoder + MLP link predictor.
// N=100000, F_IN=128, HID=64, OUT=32, E=3.2M edges, EL=1M label edges.
// Inputs: float32 (x, weights, biases), int32 (edge indices).
// Output float32: [link_pred (1M) | z (100000*32)] concatenated flat.
//
// R9: agg_pull was latency-bound (serial 8-deep acc chain; 4.5TB/s effective vs
// ~25us pipe floor). Now unroll 16 + 4 independent accumulators. bhist/binA
// edge sweeps vectorized to int4.

#define BINA_CHUNK 4096

// ---------------- bucket histogram ----------------

__global__ __launch_bounds__(256) void bhist_kernel(const int* __restrict__ colv,
                                                    int* __restrict__ bcount,
                                                    int E, int nbuck) {
    __shared__ int hist[800];
    int base = blockIdx.x * BINA_CHUNK;
    int end = min(base + BINA_CHUNK, E);
    for (int i = threadIdx.x; i < nbuck; i += 256) hist[i] = 0;
    __syncthreads();
    int e = base + threadIdx.x * 4;
    for (; e + 4 <= end; e += 1024) {
        int4 c4 = *(const int4*)&colv[e];
        atomicAdd(&hist[c4.x >> 7], 1);
        atomicAdd(&hist[c4.y >> 7], 1);
        atomicAdd(&hist[c4.z >> 7], 1);
        atomicAdd(&hist[c4.w >> 7], 1);
    }
    for (; e < end; ++e) atomicAdd(&hist[colv[e] >> 7], 1);
    __syncthreads();
    for (int b = threadIdx.x; b < nbuck; b += 256) {
        int c = hist[b];
        if (c > 0) atomicAdd(&bcount[b], c);
    }
}

// ---------------- bucket scan ----------------

__global__ __launch_bounds__(256) void bscan_kernel(const int* __restrict__ bcount,
                                                    int* __restrict__ bbase,
                                                    int* __restrict__ bcur,
                                                    int nbuck, int* __restrict__ offsets, int N) {
    __shared__ int sh[256];
    int base = threadIdx.x * 4;
    int v[4]; int tsum = 0;
#pragma unroll
    for (int i = 0; i < 4; ++i) { int idx = base + i; v[i] = (idx < nbuck) ? bcount[idx] : 0; tsum += v[i]; }
    sh[threadIdx.x] = tsum;
    __syncthreads();
#pragma unroll
    for (int off = 1; off < 256; off <<= 1) {
        int y = (threadIdx.x >= (unsigned)off) ? sh[threadIdx.x - off] : 0;
        __syncthreads();
        sh[threadIdx.x] += y;
        __syncthreads();
    }
    int ex = sh[threadIdx.x] - tsum;
#pragma unroll
    for (int i = 0; i < 4; ++i) {
        int idx = base + i;
        if (idx < nbuck) { bbase[idx] = ex; bcur[idx] = ex; ex += v[i]; }
        else if (idx == nbuck) { bbase[idx] = ex; offsets[N] = ex; }  // = E
    }
}

// ---------------- Phase A: block-local counting sort into buckets ----------------

__global__ __launch_bounds__(256) void binA_kernel(const int* __restrict__ rowv,
                                                   const int* __restrict__ colv,
                                                   int* __restrict__ bcur,
                                                   int* __restrict__ pairs,
                                                   int E, int nbuck) {
    __shared__ int hist[800];
    __shared__ int pos[800];
    int base = blockIdx.x * BINA_CHUNK;
    int end = min(base + BINA_CHUNK, E);
    for (int i = threadIdx.x; i < nbuck; i += 256) hist[i] = 0;
    __syncthreads();
    {
        int e = base + threadIdx.x * 4;
        for (; e + 4 <= end; e += 1024) {
            int4 c4 = *(const int4*)&colv[e];
            atomicAdd(&hist[c4.x >> 7], 1);
            atomicAdd(&hist[c4.y >> 7], 1);
            atomicAdd(&hist[c4.z >> 7], 1);
            atomicAdd(&hist[c4.w >> 7], 1);
        }
        for (; e < end; ++e) atomicAdd(&hist[colv[e] >> 7], 1);
    }
    __syncthreads();
    for (int b = threadIdx.x; b < nbuck; b += 256) {
        int c = hist[b];
        pos[b] = (c > 0) ? atomicAdd(&bcur[b], c) : 0;
    }
    __syncthreads();
    {
        int e = base + threadIdx.x * 4;
        for (; e + 4 <= end; e += 1024) {
            int4 c4 = *(const int4*)&colv[e];
            int4 r4 = *(const int4*)&rowv[e];
            int g0 = atomicAdd(&pos[c4.x >> 7], 1); pairs[g0] = (r4.x << 7) | (c4.x & 127);
            int g1 = atomicAdd(&pos[c4.y >> 7], 1); pairs[g1] = (r4.y << 7) | (c4.y & 127);
            int g2 = atomicAdd(&pos[c4.z >> 7], 1); pairs[g2] = (r4.z << 7) | (c4.z & 127);
            int g3 = atomicAdd(&pos[c4.w >> 7], 1); pairs[g3] = (r4.w << 7) | (c4.w & 127);
        }
        for (; e < end; ++e) {
            int c = colv[e];
            int g = atomicAdd(&pos[c >> 7], 1);
            pairs[g] = (rowv[e] << 7) | (c & 127);
        }
    }
}

// ---------------- Phase B: per bucket — node hist, scan, offsets+dinv, scatter ----------------

__global__ __launch_bounds__(256) void binB_kernel(const int* __restrict__ pairs,
                                                   const int* __restrict__ bbase,
                                                   int* __restrict__ offsets,
                                                   float* __restrict__ dinv,
                                                   int* __restrict__ edge_src, int N) {
    __shared__ int lcnt[128];
    __shared__ int sc[128];
    __shared__ int lcur[128];
    int nodeBeg = blockIdx.x << 7;
    int segBeg = bbase[blockIdx.x];
    int segEnd = bbase[blockIdx.x + 1];
    if (threadIdx.x < 128) lcnt[threadIdx.x] = 0;
    __syncthreads();
    for (int e = segBeg + threadIdx.x; e < segEnd; e += 256)
        atomicAdd(&lcnt[pairs[e] & 127], 1);
    __syncthreads();
    int v = (threadIdx.x < 128) ? lcnt[threadIdx.x] : 0;
    if (threadIdx.x < 128) sc[threadIdx.x] = v;
    __syncthreads();
    for (int off = 1; off < 128; off <<= 1) {
        int y = 0;
        if (threadIdx.x < 128 && threadIdx.x >= (unsigned)off) y = sc[threadIdx.x - off];
        __syncthreads();
        if (threadIdx.x < 128) sc[threadIdx.x] += y;
        __syncthreads();
    }
    if (threadIdx.x < 128) {
        int ex = sc[threadIdx.x] - v;
        lcur[threadIdx.x] = ex;
        int node = nodeBeg + threadIdx.x;
        if (node < N) {
            offsets[node] = segBeg + ex;
            dinv[node] = rsqrtf((float)(v + 1));
        }
    }
    __syncthreads();
    for (int e = segBeg + threadIdx.x; e < segEnd; e += 256) {
        int p = pairs[e];
        int rel = atomicAdd(&lcur[p & 127], 1);
        edge_src[segBeg + rel] = p >> 7;
    }
}

// ---------------- GEMM + dinv scale, fp16 out ----------------

template <int K, int NOUT>
__global__ __launch_bounds__(16 * (NOUT / 4)) void gemm_scale(const float* __restrict__ in_,
                                                              const float* __restrict__ W,
                                                              const float* __restrict__ dinv,
                                                              __half* __restrict__ out, int N) {
    constexpr int TPB = 16 * (NOUT / 4);
    constexpr int XPITCH = K + 4;
    __shared__ float xs[64 * XPITCH];
    __shared__ float ws[K * NOUT];

    const int tid = threadIdx.x;
    const int nodeBase = blockIdx.x * 64;

    for (int i = tid; i < K * NOUT / 4; i += TPB)
        *(float4*)&ws[i * 4] = *(const float4*)&W[i * 4];
    for (int i = tid; i < 64 * K / 4; i += TPB) {
        int row = i / (K / 4), c = i % (K / 4);
        int src = nodeBase + row; if (src >= N) src = N - 1;
        *(float4*)&xs[row * XPITCH + c * 4] = *(const float4*)&in_[(size_t)src * K + c * 4];
    }
    __syncthreads();

    const int jg = tid % (NOUT / 4);
    const int ng = tid / (NOUT / 4);

    float acc[4][4];
#pragma unroll
    for (int i = 0; i < 4; ++i)
#pragma unroll
        for (int j = 0; j < 4; ++j) acc[i][j] = 0.f;

    for (int kc = 0; kc < K / 4; ++kc) {
        float4 xv[4], wv[4];
#pragma unroll
        for (int ni = 0; ni < 4; ++ni)
            xv[ni] = *(const float4*)&xs[(ng * 4 + ni) * XPITCH + kc * 4];
#pragma unroll
        for (int t = 0; t < 4; ++t)
            wv[t] = *(const float4*)&ws[(kc * 4 + t) * NOUT + jg * 4];
#pragma unroll
        for (int ni = 0; ni < 4; ++ni) {
            acc[ni][0] = fmaf(xv[ni].x, wv[0].x, acc[ni][0]);
            acc[ni][1] = fmaf(xv[ni].x, wv[0].y, acc[ni][1]);
            acc[ni][2] = fmaf(xv[ni].x, wv[0].z, acc[ni][2]);
            acc[ni][3] = fmaf(xv[ni].x, wv[0].w, acc[ni][3]);
            acc[ni][0] = fmaf(xv[ni].y, wv[1].x, acc[ni][0]);
            acc[ni][1] = fmaf(xv[ni].y, wv[1].y, acc[ni][1]);
            acc[ni][2] = fmaf(xv[ni].y, wv[1].z, acc[ni][2]);
            acc[ni][3] = fmaf(xv[ni].y, wv[1].w, acc[ni][3]);
            acc[ni][0] = fmaf(xv[ni].z, wv[2].x, acc[ni][0]);
            acc[ni][1] = fmaf(xv[ni].z, wv[2].y, acc[ni][1]);
            acc[ni][2] = fmaf(xv[ni].z, wv[2].z, acc[ni][2]);
            acc[ni][3] = fmaf(xv[ni].z, wv[2].w, acc[ni][3]);
            acc[ni][0] = fmaf(xv[ni].w, wv[3].x, acc[ni][0]);
            acc[ni][1] = fmaf(xv[ni].w, wv[3].y, acc[ni][1]);
            acc[ni][2] = fmaf(xv[ni].w, wv[3].z, acc[ni][2]);
            acc[ni][3] = fmaf(xv[ni].w, wv[3].w, acc[ni][3]);
        }
    }

#pragma unroll
    for (int ni = 0; ni < 4; ++ni) {
        int node = nodeBase + ng * 4 + ni;
        if (node < N) {
            float dn = dinv[node];
            __half2* op = (__half2*)(out + (size_t)node * NOUT + jg * 4);
            op[0] = __floats2half2_rn(acc[ni][0] * dn, acc[ni][1] * dn);
            op[1] = __floats2half2_rn(acc[ni][2] * dn, acc[ni][3] * dn);
        }
    }
}

// ---------------- Pull aggregation (fp16 rows, fp32 accumulate, 4 chains) ----------------

template <int F, bool RELU>
__global__ __launch_bounds__(256) void agg_pull(const __half* __restrict__ h,
                                                const float* __restrict__ dinv,
                                                const float* __restrict__ bias,
                                                const int* __restrict__ edge_src,
                                                const int* __restrict__ offsets,
                                                float* __restrict__ out, int N) {
    int lane = threadIdx.x & 63;
    int wave = blockIdx.x * (256 >> 6) + (threadIdx.x >> 6);
    constexpr int GPW = 64 / F;
    int node = wave * GPW + lane / F;
    int f = lane % F;
    if (node >= N) return;
    float dn = dinv[node];
    int beg = offsets[node], end = offsets[node + 1];
    float a0 = __half2float(h[(size_t)node * F + f]);  // self-loop
    float a1 = 0.f, a2 = 0.f, a3 = 0.f;
    int j = beg;
    for (; j + 16 <= end; j += 16) {
        int s[16];
#pragma unroll
        for (int u = 0; u < 16; ++u) s[u] = edge_src[j + u];
        float v[16];
#pragma unroll
        for (int u = 0; u < 16; ++u) v[u] = __half2float(h[(size_t)s[u] * F + f]);
#pragma unroll
        for (int u = 0; u < 16; u += 4) {
            a0 += v[u]; a1 += v[u + 1]; a2 += v[u + 2]; a3 += v[u + 3];
        }
    }
    for (; j + 4 <= end; j += 4) {
        int s0 = edge_src[j], s1 = edge_src[j + 1], s2 = edge_src[j + 2], s3 = edge_src[j + 3];
        float v0 = __half2float(h[(size_t)s0 * F + f]);
        float v1 = __half2float(h[(size_t)s1 * F + f]);
        float v2 = __half2float(h[(size_t)s2 * F + f]);
        float v3 = __half2float(h[(size_t)s3 * F + f]);
        a0 += v0; a1 += v1; a2 += v2; a3 += v3;
    }
    for (; j < end; ++j) a0 += __half2float(h[(size_t)edge_src[j] * F + f]);
    float r = ((a0 + a1) + (a2 + a3)) * dn + bias[f];
    if (RELU) r = fmaxf(r, 0.f);
    out[(size_t)node * F + f] = r;
}

// ---------------- Decode stage 1: uv[n] = [z@W1_top | z@W1_bot] (fp16 out) ----------------

__global__ __launch_bounds__(256) void gemm_uv(const float* __restrict__ z,   // [N,32]
                                               const float* __restrict__ W1,  // [64,64]
                                               __half* __restrict__ uv, int N) {
    constexpr int ZPITCH = 36;
    __shared__ float zs[64 * ZPITCH];
    __shared__ float ws[64 * 64];
    const int tid = threadIdx.x;
    const int nodeBase = blockIdx.x * 64;

    for (int i = tid; i < 64 * 64 / 4; i += 256)
        *(float4*)&ws[i * 4] = *(const float4*)&W1[i * 4];
    for (int i = tid; i < 64 * 8; i += 256) {
        int row = i / 8, c = i % 8;
        int src = nodeBase + row; if (src >= N) src = N - 1;
        *(float4*)&zs[row * ZPITCH + c * 4] = *(const float4*)&z[(size_t)src * 32 + c * 4];
    }
    __syncthreads();

    const int jg = tid % 16;
    const int ng = tid / 16;

    float au[4][4], av[4][4];
#pragma unroll
    for (int i = 0; i < 4; ++i)
#pragma unroll
        for (int j = 0; j < 4; ++j) { au[i][j] = 0.f; av[i][j] = 0.f; }

    for (int kc = 0; kc < 8; ++kc) {            // K = 32
        float4 xv[4], wu[4], wv2[4];
#pragma unroll
        for (int ni = 0; ni < 4; ++ni)
            xv[ni] = *(const float4*)&zs[(ng * 4 + ni) * ZPITCH + kc * 4];
#pragma unroll
        for (int t = 0; t < 4; ++t) {
            wu[t]  = *(const float4*)&ws[(kc * 4 + t) * 64 + jg * 4];
            wv2[t] = *(const float4*)&ws[(32 + kc * 4 + t) * 64 + jg * 4];
        }
#pragma unroll
        for (int ni = 0; ni < 4; ++ni) {
            float xk[4] = {xv[ni].x, xv[ni].y, xv[ni].z, xv[ni].w};
#pragma unroll
            for (int t = 0; t < 4; ++t) {
                au[ni][0] = fmaf(xk[t], wu[t].x, au[ni][0]);
                au[ni][1] = fmaf(xk[t], wu[t].y, au[ni][1]);
                au[ni][2] = fmaf(xk[t], wu[t].z, au[ni][2]);
                au[ni][3] = fmaf(xk[t], wu[t].w, au[ni][3]);
                av[ni][0] = fmaf(xk[t], wv2[t].x, av[ni][0]);
                av[ni][1] = fmaf(xk[t], wv2[t].y, av[ni][1]);
                av[ni][2] = fmaf(xk[t], wv2[t].z, av[ni][2]);
                av[ni][3] = fmaf(xk[t], wv2[t].w, av[ni][3]);
            }
        }
    }

#pragma unroll
    for (int ni = 0; ni < 4; ++ni) {
        int node = nodeBase + ng * 4 + ni;
        if (node < N) {
            __half2* pu = (__half2*)(uv + (size_t)node * 128 + jg * 4);
            pu[0] = __floats2half2_rn(au[ni][0], au[ni][1]);
            pu[1] = __floats2half2_rn(au[ni][2], au[ni][3]);
            __half2* pv = (__half2*)(uv + (size_t)node * 128 + 64 + jg * 4);
            pv[0] = __floats2half2_rn(av[ni][0], av[ni][1]);
            pv[1] = __floats2half2_rn(av[ni][2], av[ni][3]);
        }
    }
}

// ---------------- Decode stage 2: link_pred[e] = relu(u[a]+v[b]+b1)·w2 + b2 ----------------

__global__ __launch_bounds__(256) void decode_edge(const __half* __restrict__ uv,
                                                   const int* __restrict__ eli, int EL,
                                                   const float* __restrict__ lpb1,
                                                   const float* __restrict__ lpW2,
                                                   const float* __restrict__ lpb2,
                                                   float* __restrict__ out) {
    const int sub = threadIdx.x & 15;
    float4 b1r = *(const float4*)&lpb1[sub * 4];
    float4 w2r = *(const float4*)&lpW2[sub * 4];
    const float b2v = lpb2[0];
    int e = blockIdx.x * 16 + (threadIdx.x >> 4);
    if (e >= EL) return;
    int a = eli[e], b = eli[EL + e];
    const __half2* pa = (const __half2*)(uv + (size_t)a * 128 + sub * 4);
    const __half2* pb = (const __half2*)(uv + (size_t)b * 128 + 64 + sub * 4);
    float2 a01 = __half22float2(pa[0]), a23 = __half22float2(pa[1]);
    float2 b01 = __half22float2(pb[0]), b23 = __half22float2(pb[1]);
    float p = fmaxf(a01.x + b01.x + b1r.x, 0.f) * w2r.x;
    p = fmaf(fmaxf(a01.y + b01.y + b1r.y, 0.f), w2r.y, p);
    p = fmaf(fmaxf(a23.x + b23.x + b1r.z, 0.f), w2r.z, p);
    p = fmaf(fmaxf(a23.y + b23.y + b1r.w, 0.f), w2r.w, p);
    p += __shfl_down(p, 8, 16);
    p += __shfl_down(p, 4, 16);
    p += __shfl_down(p, 2, 16);
    p += __shfl_down(p, 1, 16);
    if (sub == 0) out[e] = p + b2v;
}

// ---------------- launch ----------------

extern "C" void kernel_launch(void* const* d_in, const int* in_sizes, int n_in,
                              void* d_out, int out_size, void* d_ws, size_t ws_size,
                              hipStream_t stream) {
    const float* x    = (const float*)d_in[0];
    const int* ei     = (const int*)d_in[1];
    const int* eli    = (const int*)d_in[2];
    const float* W1   = (const float*)d_in[3];
    const float* b1   = (const float*)d_in[4];
    const float* W2   = (const float*)d_in[5];
    const float* b2   = (const float*)d_in[6];
    const float* W3   = (const float*)d_in[7];
    const float* b3   = (const float*)d_in[8];
    const float* lpW1 = (const float*)d_in[9];
    const float* lpb1 = (const float*)d_in[10];
    const float* lpW2 = (const float*)d_in[11];
    const float* lpb2 = (const float*)d_in[12];

    const int N  = in_sizes[0] / 128;   // 100000
    const int E  = in_sizes[1] / 2;     // 3200000
    const int EL = in_sizes[2] / 2;     // 1000000

    char* p = (char*)d_ws;
    auto alloc = [&](size_t bytes) { void* r = (void*)p; p += (bytes + 255) & ~(size_t)255; return r; };
    float* dinv     = (float*)alloc((size_t)N * 4);
    int*   offsets  = (int*)alloc((size_t)(N + 1) * 4);
    int*   bcount   = (int*)alloc(1024 * 4);
    int*   bbase    = (int*)alloc(1024 * 4);
    int*   bcur     = (int*)alloc(1024 * 4);
    int*   edge_src = (int*)alloc((size_t)E * 4);
    __half* bufG    = (__half*)alloc((size_t)N * 64 * 2);   // fp16 messages h'
    float* bufZ     = (float*)alloc((size_t)N * 64 * 4);    // fp32 z1/z2
    __half* uvbuf   = (__half*)alloc((size_t)N * 128 * 2);  // fp16 uv
    int*   pairs    = (int*)uvbuf;  // alias: pairs (12.8MB) dead before gemm_uv writes uv

    const int* rowv = ei;        // edge_index[0] = source
    const int* colv = ei + E;    // edge_index[1] = target

    int nbuk = (N + 127) / 128;  // 782
    int nchunk = (E + BINA_CHUNK - 1) / BINA_CHUNK;

    hipMemsetAsync(bcount, 0, (size_t)nbuk * 4, stream);
    bhist_kernel<<<nchunk, 256, 0, stream>>>(colv, bcount, E, nbuk);
    bscan_kernel<<<1, 256, 0, stream>>>(bcount, bbase, bcur, nbuk, offsets, N);
    binA_kernel<<<nchunk, 256, 0, stream>>>(rowv, colv, bcur, pairs, E, nbuk);
    binB_kernel<<<nbuk, 256, 0, stream>>>(pairs, bbase, offsets, dinv, edge_src, N);

    float* zout = (float*)d_out + EL;   // z lives in the output tail (float32)

    int gblocks = (N + 63) / 64;  // 1563

    // layer 1: x[N,128] -> bufG h' (fp16) -> bufZ (fp32, relu)
    gemm_scale<128, 64><<<gblocks, 256, 0, stream>>>(x, W1, dinv, bufG, N);
    agg_pull<64, true><<<(N + 3) / 4, 256, 0, stream>>>(bufG, dinv, b1, edge_src, offsets, bufZ, N);
    // layer 2
    gemm_scale<64, 64><<<gblocks, 256, 0, stream>>>(bufZ, W2, dinv, bufG, N);
    agg_pull<64, true><<<(N + 3) / 4, 256, 0, stream>>>(bufG, dinv, b2, edge_src, offsets, bufZ, N);
    // layer 3: 32-wide, write z directly into d_out tail
    gemm_scale<64, 32><<<gblocks, 128, 0, stream>>>(bufZ, W3, dinv, bufG, N);
    agg_pull<32, false><<<(N + 7) / 8, 256, 0, stream>>>(bufG, dinv, b3, edge_src, offsets, zout, N);
    // decode: per-node uv precompute (fp16), then per-edge gather+epilogue
    gemm_uv<<<gblocks, 256, 0, stream>>>(zout, lpW1, uvbuf, N);
    decode_edge<<<(EL + 15) / 16, 256, 0, stream>>>(uvbuf, eli, EL, lpb1, lpW2, lpb2, (float*)d_out);
}

// Round 11
// 581.457 us; speedup vs baseline: 2.8483x; 1.0544x over previous
//
#include <hip/hip_runtime.h>
#include <hip/hip_bf16.h>
#include <hip/hip_fp16.h>

// MusicGNN — 3-layer GCN encoder + MLP link predictor.
// N=100000, F_IN=128, HID=64, OUT=32, E=3.2M edges, EL=1M label edges.
// Inputs: float32 (x, weights, biases), int32 (edge indices).
// Output float32: [link_pred (1M) | z (100000*32)] concatenated flat.
//
// R10: agg_pull converging to VALU-inst-bound (51% VALUBusy, ~4.5 insts per
// feature-edge at 2B/lane loads). Packed __half2 gathers: 2 features/lane,
// 2 nodes/wave (F=64) or 4 (F=32), per-subgroup edge walks. ~2x fewer
// wave-insts per edge. fp32 accumulation unchanged.

#define BINA_CHUNK 4096

// ---------------- bucket histogram ----------------

__global__ __launch_bounds__(256) void bhist_kernel(const int* __restrict__ colv,
                                                    int* __restrict__ bcount,
                                                    int E, int nbuck) {
    __shared__ int hist[800];
    int base = blockIdx.x * BINA_CHUNK;
    int end = min(base + BINA_CHUNK, E);
    for (int i = threadIdx.x; i < nbuck; i += 256) hist[i] = 0;
    __syncthreads();
    int e = base + threadIdx.x * 4;
    for (; e + 4 <= end; e += 1024) {
        int4 c4 = *(const int4*)&colv[e];
        atomicAdd(&hist[c4.x >> 7], 1);
        atomicAdd(&hist[c4.y >> 7], 1);
        atomicAdd(&hist[c4.z >> 7], 1);
        atomicAdd(&hist[c4.w >> 7], 1);
    }
    for (; e < end; ++e) atomicAdd(&hist[colv[e] >> 7], 1);
    __syncthreads();
    for (int b = threadIdx.x; b < nbuck; b += 256) {
        int c = hist[b];
        if (c > 0) atomicAdd(&bcount[b], c);
    }
}

// ---------------- bucket scan ----------------

__global__ __launch_bounds__(256) void bscan_kernel(const int* __restrict__ bcount,
                                                    int* __restrict__ bbase,
                                                    int* __restrict__ bcur,
                                                    int nbuck, int* __restrict__ offsets, int N) {
    __shared__ int sh[256];
    int base = threadIdx.x * 4;
    int v[4]; int tsum = 0;
#pragma unroll
    for (int i = 0; i < 4; ++i) { int idx = base + i; v[i] = (idx < nbuck) ? bcount[idx] : 0; tsum += v[i]; }
    sh[threadIdx.x] = tsum;
    __syncthreads();
#pragma unroll
    for (int off = 1; off < 256; off <<= 1) {
        int y = (threadIdx.x >= (unsigned)off) ? sh[threadIdx.x - off] : 0;
        __syncthreads();
        sh[threadIdx.x] += y;
        __syncthreads();
    }
    int ex = sh[threadIdx.x] - tsum;
#pragma unroll
    for (int i = 0; i < 4; ++i) {
        int idx = base + i;
        if (idx < nbuck) { bbase[idx] = ex; bcur[idx] = ex; ex += v[i]; }
        else if (idx == nbuck) { bbase[idx] = ex; offsets[N] = ex; }  // = E
    }
}

// ---------------- Phase A: block-local counting sort into buckets ----------------

__global__ __launch_bounds__(256) void binA_kernel(const int* __restrict__ rowv,
                                                   const int* __restrict__ colv,
                                                   int* __restrict__ bcur,
                                                   int* __restrict__ pairs,
                                                   int E, int nbuck) {
    __shared__ int hist[800];
    __shared__ int pos[800];
    int base = blockIdx.x * BINA_CHUNK;
    int end = min(base + BINA_CHUNK, E);
    for (int i = threadIdx.x; i < nbuck; i += 256) hist[i] = 0;
    __syncthreads();
    {
        int e = base + threadIdx.x * 4;
        for (; e + 4 <= end; e += 1024) {
            int4 c4 = *(const int4*)&colv[e];
            atomicAdd(&hist[c4.x >> 7], 1);
            atomicAdd(&hist[c4.y >> 7], 1);
            atomicAdd(&hist[c4.z >> 7], 1);
            atomicAdd(&hist[c4.w >> 7], 1);
        }
        for (; e < end; ++e) atomicAdd(&hist[colv[e] >> 7], 1);
    }
    __syncthreads();
    for (int b = threadIdx.x; b < nbuck; b += 256) {
        int c = hist[b];
        pos[b] = (c > 0) ? atomicAdd(&bcur[b], c) : 0;
    }
    __syncthreads();
    {
        int e = base + threadIdx.x * 4;
        for (; e + 4 <= end; e += 1024) {
            int4 c4 = *(const int4*)&colv[e];
            int4 r4 = *(const int4*)&rowv[e];
            int g0 = atomicAdd(&pos[c4.x >> 7], 1); pairs[g0] = (r4.x << 7) | (c4.x & 127);
            int g1 = atomicAdd(&pos[c4.y >> 7], 1); pairs[g1] = (r4.y << 7) | (c4.y & 127);
            int g2 = atomicAdd(&pos[c4.z >> 7], 1); pairs[g2] = (r4.z << 7) | (c4.z & 127);
            int g3 = atomicAdd(&pos[c4.w >> 7], 1); pairs[g3] = (r4.w << 7) | (c4.w & 127);
        }
        for (; e < end; ++e) {
            int c = colv[e];
            int g = atomicAdd(&pos[c >> 7], 1);
            pairs[g] = (rowv[e] << 7) | (c & 127);
        }
    }
}

// ---------------- Phase B: per bucket — node hist, scan, offsets+dinv, scatter ----------------

__global__ __launch_bounds__(256) void binB_kernel(const int* __restrict__ pairs,
                                                   const int* __restrict__ bbase,
                                                   int* __restrict__ offsets,
                                                   float* __restrict__ dinv,
                                                   int* __restrict__ edge_src, int N) {
    __shared__ int lcnt[128];
    __shared__ int sc[128];
    __shared__ int lcur[128];
    int nodeBeg = blockIdx.x << 7;
    int segBeg = bbase[blockIdx.x];
    int segEnd = bbase[blockIdx.x + 1];
    if (threadIdx.x < 128) lcnt[threadIdx.x] = 0;
    __syncthreads();
    for (int e = segBeg + threadIdx.x; e < segEnd; e += 256)
        atomicAdd(&lcnt[pairs[e] & 127], 1);
    __syncthreads();
    int v = (threadIdx.x < 128) ? lcnt[threadIdx.x] : 0;
    if (threadIdx.x < 128) sc[threadIdx.x] = v;
    __syncthreads();
    for (int off = 1; off < 128; off <<= 1) {
        int y = 0;
        if (threadIdx.x < 128 && threadIdx.x >= (unsigned)off) y = sc[threadIdx.x - off];
        __syncthreads();
        if (threadIdx.x < 128) sc[threadIdx.x] += y;
        __syncthreads();
    }
    if (threadIdx.x < 128) {
        int ex = sc[threadIdx.x] - v;
        lcur[threadIdx.x] = ex;
        int node = nodeBeg + threadIdx.x;
        if (node < N) {
            offsets[node] = segBeg + ex;
            dinv[node] = rsqrtf((float)(v + 1));
        }
    }
    __syncthreads();
    for (int e = segBeg + threadIdx.x; e < segEnd; e += 256) {
        int p = pairs[e];
        int rel = atomicAdd(&lcur[p & 127], 1);
        edge_src[segBeg + rel] = p >> 7;
    }
}

// ---------------- GEMM + dinv scale, fp16 out ----------------

template <int K, int NOUT>
__global__ __launch_bounds__(16 * (NOUT / 4)) void gemm_scale(const float* __restrict__ in_,
                                                              const float* __restrict__ W,
                                                              const float* __restrict__ dinv,
                                                              __half* __restrict__ out, int N) {
    constexpr int TPB = 16 * (NOUT / 4);
    constexpr int XPITCH = K + 4;
    __shared__ float xs[64 * XPITCH];
    __shared__ float ws[K * NOUT];

    const int tid = threadIdx.x;
    const int nodeBase = blockIdx.x * 64;

    for (int i = tid; i < K * NOUT / 4; i += TPB)
        *(float4*)&ws[i * 4] = *(const float4*)&W[i * 4];
    for (int i = tid; i < 64 * K / 4; i += TPB) {
        int row = i / (K / 4), c = i % (K / 4);
        int src = nodeBase + row; if (src >= N) src = N - 1;
        *(float4*)&xs[row * XPITCH + c * 4] = *(const float4*)&in_[(size_t)src * K + c * 4];
    }
    __syncthreads();

    const int jg = tid % (NOUT / 4);
    const int ng = tid / (NOUT / 4);

    float acc[4][4];
#pragma unroll
    for (int i = 0; i < 4; ++i)
#pragma unroll
        for (int j = 0; j < 4; ++j) acc[i][j] = 0.f;

    for (int kc = 0; kc < K / 4; ++kc) {
        float4 xv[4], wv[4];
#pragma unroll
        for (int ni = 0; ni < 4; ++ni)
            xv[ni] = *(const float4*)&xs[(ng * 4 + ni) * XPITCH + kc * 4];
#pragma unroll
        for (int t = 0; t < 4; ++t)
            wv[t] = *(const float4*)&ws[(kc * 4 + t) * NOUT + jg * 4];
#pragma unroll
        for (int ni = 0; ni < 4; ++ni) {
            acc[ni][0] = fmaf(xv[ni].x, wv[0].x, acc[ni][0]);
            acc[ni][1] = fmaf(xv[ni].x, wv[0].y, acc[ni][1]);
            acc[ni][2] = fmaf(xv[ni].x, wv[0].z, acc[ni][2]);
            acc[ni][3] = fmaf(xv[ni].x, wv[0].w, acc[ni][3]);
            acc[ni][0] = fmaf(xv[ni].y, wv[1].x, acc[ni][0]);
            acc[ni][1] = fmaf(xv[ni].y, wv[1].y, acc[ni][1]);
            acc[ni][2] = fmaf(xv[ni].y, wv[1].z, acc[ni][2]);
            acc[ni][3] = fmaf(xv[ni].y, wv[1].w, acc[ni][3]);
            acc[ni][0] = fmaf(xv[ni].z, wv[2].x, acc[ni][0]);
            acc[ni][1] = fmaf(xv[ni].z, wv[2].y, acc[ni][1]);
            acc[ni][2] = fmaf(xv[ni].z, wv[2].z, acc[ni][2]);
            acc[ni][3] = fmaf(xv[ni].z, wv[2].w, acc[ni][3]);
            acc[ni][0] = fmaf(xv[ni].w, wv[3].x, acc[ni][0]);
            acc[ni][1] = fmaf(xv[ni].w, wv[3].y, acc[ni][1]);
            acc[ni][2] = fmaf(xv[ni].w, wv[3].z, acc[ni][2]);
            acc[ni][3] = fmaf(xv[ni].w, wv[3].w, acc[ni][3]);
        }
    }

#pragma unroll
    for (int ni = 0; ni < 4; ++ni) {
        int node = nodeBase + ng * 4 + ni;
        if (node < N) {
            float dn = dinv[node];
            __half2* op = (__half2*)(out + (size_t)node * NOUT + jg * 4);
            op[0] = __floats2half2_rn(acc[ni][0] * dn, acc[ni][1] * dn);
            op[1] = __floats2half2_rn(acc[ni][2] * dn, acc[ni][3] * dn);
        }
    }
}

// ---------------- Pull aggregation: packed half2 gathers, fp32 accumulate ----------------
// Each lane handles 2 features; F/2 lanes per node; 128/F nodes per wave.
// Sub-groups walk their own edge lists (exec-mask divergence).

template <int F, bool RELU>
__global__ __launch_bounds__(256) void agg_pull(const __half* __restrict__ h,
                                                const float* __restrict__ dinv,
                                                const float* __restrict__ bias,
                                                const int* __restrict__ edge_src,
                                                const int* __restrict__ offsets,
                                                float* __restrict__ out, int N) {
    constexpr int LPN = F / 2;        // lanes per node
    constexpr int GPW = 64 / LPN;     // nodes per wave
    int lane = threadIdx.x & 63;
    int wave = (blockIdx.x * 256 + (int)threadIdx.x) >> 6;
    int g = lane / LPN;
    int fl = lane % LPN;              // feature-pair index
    int node = wave * GPW + g;
    if (node >= N) return;
    float dn = dinv[node];
    int beg = offsets[node], end = offsets[node + 1];
    const __half2* __restrict__ hp = (const __half2*)h;

    float2 sv = __half22float2(hp[(size_t)node * LPN + fl]);  // self-loop
    float a0x = sv.x, a0y = sv.y;
    float a1x = 0.f, a1y = 0.f, a2x = 0.f, a2y = 0.f, a3x = 0.f, a3y = 0.f;

    int j = beg;
    for (; j + 8 <= end; j += 8) {
        int s0 = edge_src[j],     s1 = edge_src[j + 1], s2 = edge_src[j + 2], s3 = edge_src[j + 3];
        int s4 = edge_src[j + 4], s5 = edge_src[j + 5], s6 = edge_src[j + 6], s7 = edge_src[j + 7];
        __half2 v0 = hp[(size_t)s0 * LPN + fl];
        __half2 v1 = hp[(size_t)s1 * LPN + fl];
        __half2 v2 = hp[(size_t)s2 * LPN + fl];
        __half2 v3 = hp[(size_t)s3 * LPN + fl];
        __half2 v4 = hp[(size_t)s4 * LPN + fl];
        __half2 v5 = hp[(size_t)s5 * LPN + fl];
        __half2 v6 = hp[(size_t)s6 * LPN + fl];
        __half2 v7 = hp[(size_t)s7 * LPN + fl];
        float2 f0 = __half22float2(v0), f1 = __half22float2(v1);
        float2 f2 = __half22float2(v2), f3 = __half22float2(v3);
        float2 f4 = __half22float2(v4), f5 = __half22float2(v5);
        float2 f6 = __half22float2(v6), f7 = __half22float2(v7);
        a0x += f0.x; a0y += f0.y; a1x += f1.x; a1y += f1.y;
        a2x += f2.x; a2y += f2.y; a3x += f3.x; a3y += f3.y;
        a0x += f4.x; a0y += f4.y; a1x += f5.x; a1y += f5.y;
        a2x += f6.x; a2y += f6.y; a3x += f7.x; a3y += f7.y;
    }
    for (; j + 2 <= end; j += 2) {
        int s0 = edge_src[j], s1 = edge_src[j + 1];
        float2 f0 = __half22float2(hp[(size_t)s0 * LPN + fl]);
        float2 f1 = __half22float2(hp[(size_t)s1 * LPN + fl]);
        a0x += f0.x; a0y += f0.y; a1x += f1.x; a1y += f1.y;
    }
    if (j < end) {
        float2 f0 = __half22float2(hp[(size_t)edge_src[j] * LPN + fl]);
        a0x += f0.x; a0y += f0.y;
    }

    float2 bv = *(const float2*)&bias[fl * 2];
    float rx = ((a0x + a1x) + (a2x + a3x)) * dn + bv.x;
    float ry = ((a0y + a1y) + (a2y + a3y)) * dn + bv.y;
    if (RELU) { rx = fmaxf(rx, 0.f); ry = fmaxf(ry, 0.f); }
    *(float2*)&out[(size_t)node * F + fl * 2] = make_float2(rx, ry);
}

// ---------------- Decode stage 1: uv[n] = [z@W1_top | z@W1_bot] (fp16 out) ----------------

__global__ __launch_bounds__(256) void gemm_uv(const float* __restrict__ z,   // [N,32]
                                               const float* __restrict__ W1,  // [64,64]
                                               __half* __restrict__ uv, int N) {
    constexpr int ZPITCH = 36;
    __shared__ float zs[64 * ZPITCH];
    __shared__ float ws[64 * 64];
    const int tid = threadIdx.x;
    const int nodeBase = blockIdx.x * 64;

    for (int i = tid; i < 64 * 64 / 4; i += 256)
        *(float4*)&ws[i * 4] = *(const float4*)&W1[i * 4];
    for (int i = tid; i < 64 * 8; i += 256) {
        int row = i / 8, c = i % 8;
        int src = nodeBase + row; if (src >= N) src = N - 1;
        *(float4*)&zs[row * ZPITCH + c * 4] = *(const float4*)&z[(size_t)src * 32 + c * 4];
    }
    __syncthreads();

    const int jg = tid % 16;
    const int ng = tid / 16;

    float au[4][4], av[4][4];
#pragma unroll
    for (int i = 0; i < 4; ++i)
#pragma unroll
        for (int j = 0; j < 4; ++j) { au[i][j] = 0.f; av[i][j] = 0.f; }

    for (int kc = 0; kc < 8; ++kc) {            // K = 32
        float4 xv[4], wu[4], wv2[4];
#pragma unroll
        for (int ni = 0; ni < 4; ++ni)
            xv[ni] = *(const float4*)&zs[(ng * 4 + ni) * ZPITCH + kc * 4];
#pragma unroll
        for (int t = 0; t < 4; ++t) {
            wu[t]  = *(const float4*)&ws[(kc * 4 + t) * 64 + jg * 4];
            wv2[t] = *(const float4*)&ws[(32 + kc * 4 + t) * 64 + jg * 4];
        }
#pragma unroll
        for (int ni = 0; ni < 4; ++ni) {
            float xk[4] = {xv[ni].x, xv[ni].y, xv[ni].z, xv[ni].w};
#pragma unroll
            for (int t = 0; t < 4; ++t) {
                au[ni][0] = fmaf(xk[t], wu[t].x, au[ni][0]);
                au[ni][1] = fmaf(xk[t], wu[t].y, au[ni][1]);
                au[ni][2] = fmaf(xk[t], wu[t].z, au[ni][2]);
                au[ni][3] = fmaf(xk[t], wu[t].w, au[ni][3]);
                av[ni][0] = fmaf(xk[t], wv2[t].x, av[ni][0]);
                av[ni][1] = fmaf(xk[t], wv2[t].y, av[ni][1]);
                av[ni][2] = fmaf(xk[t], wv2[t].z, av[ni][2]);
                av[ni][3] = fmaf(xk[t], wv2[t].w, av[ni][3]);
            }
        }
    }

#pragma unroll
    for (int ni = 0; ni < 4; ++ni) {
        int node = nodeBase + ng * 4 + ni;
        if (node < N) {
            __half2* pu = (__half2*)(uv + (size_t)node * 128 + jg * 4);
            pu[0] = __floats2half2_rn(au[ni][0], au[ni][1]);
            pu[1] = __floats2half2_rn(au[ni][2], au[ni][3]);
            __half2* pv = (__half2*)(uv + (size_t)node * 128 + 64 + jg * 4);
            pv[0] = __floats2half2_rn(av[ni][0], av[ni][1]);
            pv[1] = __floats2half2_rn(av[ni][2], av[ni][3]);
        }
    }
}

// ---------------- Decode stage 2: link_pred[e] = relu(u[a]+v[b]+b1)·w2 + b2 ----------------

__global__ __launch_bounds__(256) void decode_edge(const __half* __restrict__ uv,
                                                   const int* __restrict__ eli, int EL,
                                                   const float* __restrict__ lpb1,
                                                   const float* __restrict__ lpW2,
                                                   const float* __restrict__ lpb2,
                                                   float* __restrict__ out) {
    const int sub = threadIdx.x & 15;
    float4 b1r = *(const float4*)&lpb1[sub * 4];
    float4 w2r = *(const float4*)&lpW2[sub * 4];
    const float b2v = lpb2[0];
    int e = blockIdx.x * 16 + (threadIdx.x >> 4);
    if (e >= EL) return;
    int a = eli[e], b = eli[EL + e];
    const __half2* pa = (const __half2*)(uv + (size_t)a * 128 + sub * 4);
    const __half2* pb = (const __half2*)(uv + (size_t)b * 128 + 64 + sub * 4);
    float2 a01 = __half22float2(pa[0]), a23 = __half22float2(pa[1]);
    float2 b01 = __half22float2(pb[0]), b23 = __half22float2(pb[1]);
    float p = fmaxf(a01.x + b01.x + b1r.x, 0.f) * w2r.x;
    p = fmaf(fmaxf(a01.y + b01.y + b1r.y, 0.f), w2r.y, p);
    p = fmaf(fmaxf(a23.x + b23.x + b1r.z, 0.f), w2r.z, p);
    p = fmaf(fmaxf(a23.y + b23.y + b1r.w, 0.f), w2r.w, p);
    p += __shfl_down(p, 8, 16);
    p += __shfl_down(p, 4, 16);
    p += __shfl_down(p, 2, 16);
    p += __shfl_down(p, 1, 16);
    if (sub == 0) out[e] = p + b2v;
}

// ---------------- launch ----------------

extern "C" void kernel_launch(void* const* d_in, const int* in_sizes, int n_in,
                              void* d_out, int out_size, void* d_ws, size_t ws_size,
                              hipStream_t stream) {
    const float* x    = (const float*)d_in[0];
    const int* ei     = (const int*)d_in[1];
    const int* eli    = (const int*)d_in[2];
    const float* W1   = (const float*)d_in[3];
    const float* b1   = (const float*)d_in[4];
    const float* W2   = (const float*)d_in[5];
    const float* b2   = (const float*)d_in[6];
    const float* W3   = (const float*)d_in[7];
    const float* b3   = (const float*)d_in[8];
    const float* lpW1 = (const float*)d_in[9];
    const float* lpb1 = (const float*)d_in[10];
    const float* lpW2 = (const float*)d_in[11];
    const float* lpb2 = (const float*)d_in[12];

    const int N  = in_sizes[0] / 128;   // 100000
    const int E  = in_sizes[1] / 2;     // 3200000
    const int EL = in_sizes[2] / 2;     // 1000000

    char* p = (char*)d_ws;
    auto alloc = [&](size_t bytes) { void* r = (void*)p; p += (bytes + 255) & ~(size_t)255; return r; };
    float* dinv     = (float*)alloc((size_t)N * 4);
    int*   offsets  = (int*)alloc((size_t)(N + 1) * 4);
    int*   bcount   = (int*)alloc(1024 * 4);
    int*   bbase    = (int*)alloc(1024 * 4);
    int*   bcur     = (int*)alloc(1024 * 4);
    int*   edge_src = (int*)alloc((size_t)E * 4);
    __half* bufG    = (__half*)alloc((size_t)N * 64 * 2);   // fp16 messages h'
    float* bufZ     = (float*)alloc((size_t)N * 64 * 4);    // fp32 z1/z2
    __half* uvbuf   = (__half*)alloc((size_t)N * 128 * 2);  // fp16 uv
    int*   pairs    = (int*)uvbuf;  // alias: pairs (12.8MB) dead before gemm_uv writes uv

    const int* rowv = ei;        // edge_index[0] = source
    const int* colv = ei + E;    // edge_index[1] = target

    int nbuk = (N + 127) / 128;  // 782
    int nchunk = (E + BINA_CHUNK - 1) / BINA_CHUNK;

    hipMemsetAsync(bcount, 0, (size_t)nbuk * 4, stream);
    bhist_kernel<<<nchunk, 256, 0, stream>>>(colv, bcount, E, nbuk);
    bscan_kernel<<<1, 256, 0, stream>>>(bcount, bbase, bcur, nbuk, offsets, N);
    binA_kernel<<<nchunk, 256, 0, stream>>>(rowv, colv, bcur, pairs, E, nbuk);
    binB_kernel<<<nbuk, 256, 0, stream>>>(pairs, bbase, offsets, dinv, edge_src, N);

    float* zout = (float*)d_out + EL;   // z lives in the output tail (float32)

    int gblocks = (N + 63) / 64;  // 1563

    // agg_pull packed: GPW = 128/F nodes per wave; 4 waves per block.
    int aggblocks64 = (N + 7) / 8;     // F=64: 2 nodes/wave * 4 waves
    int aggblocks32 = (N + 15) / 16;   // F=32: 4 nodes/wave * 4 waves

    // layer 1: x[N,128] -> bufG h' (fp16) -> bufZ (fp32, relu)
    gemm_scale<128, 64><<<gblocks, 256, 0, stream>>>(x, W1, dinv, bufG, N);
    agg_pull<64, true><<<aggblocks64, 256, 0, stream>>>(bufG, dinv, b1, edge_src, offsets, bufZ, N);
    // layer 2
    gemm_scale<64, 64><<<gblocks, 256, 0, stream>>>(bufZ, W2, dinv, bufG, N);
    agg_pull<64, true><<<aggblocks64, 256, 0, stream>>>(bufG, dinv, b2, edge_src, offsets, bufZ, N);
    // layer 3: 32-wide, write z directly into d_out tail
    gemm_scale<64, 32><<<gblocks, 128, 0, stream>>>(bufZ, W3, dinv, bufG, N);
    agg_pull<32, false><<<aggblocks32, 256, 0, stream>>>(bufG, dinv, b3, edge_src, offsets, zout, N);
    // decode: per-node uv precompute (fp16), then per-edge gather+epilogue
    gemm_uv<<<gblocks, 256, 0, stream>>>(zout, lpW1, uvbuf, N);
    decode_edge<<<(EL + 15) / 16, 256, 0, stream>>>(uvbuf, eli, EL, lpb1, lpW2, lpb2, (float*)d_out);
}

// Round 12
// 573.130 us; speedup vs baseline: 2.8897x; 1.0145x over previous
//
#include <hip/hip_runtime.h>
#include <hip/hip_bf16.h>
#include <hip/hip_fp16.h>

// MusicGNN — 3-layer GCN encoder + MLP link predictor.
// N=100000, F_IN=128, HID=64, OUT=32, E=3.2M edges, EL=1M label edges.
// Inputs: float32 (x, weights, biases), int32 (edge indices).
// Output float32: [link_pred (1M) | z (100000*32)] concatenated flat.
//
// R11: binA was latency-bound with idle pipes (VALU 1.4%, occupancy 22%:
// 782 blocks x 4 waves ~ 3 blocks/CU, long serial LDS-atomic chains).
// bhist/binA/binB now run 512 threads/block (8 waves): halves per-thread
// chain, doubles resident waves. Chunking/locality unchanged.

#define BINA_CHUNK 4096

// ---------------- bucket histogram ----------------

__global__ __launch_bounds__(512) void bhist_kernel(const int* __restrict__ colv,
                                                    int* __restrict__ bcount,
                                                    int E, int nbuck) {
    __shared__ int hist[800];
    int base = blockIdx.x * BINA_CHUNK;
    int end = min(base + BINA_CHUNK, E);
    for (int i = threadIdx.x; i < nbuck; i += 512) hist[i] = 0;
    __syncthreads();
    int e = base + threadIdx.x * 4;
    for (; e + 4 <= end; e += 2048) {
        int4 c4 = *(const int4*)&colv[e];
        atomicAdd(&hist[c4.x >> 7], 1);
        atomicAdd(&hist[c4.y >> 7], 1);
        atomicAdd(&hist[c4.z >> 7], 1);
        atomicAdd(&hist[c4.w >> 7], 1);
    }
    for (; e < end; ++e) atomicAdd(&hist[colv[e] >> 7], 1);
    __syncthreads();
    for (int b = threadIdx.x; b < nbuck; b += 512) {
        int c = hist[b];
        if (c > 0) atomicAdd(&bcount[b], c);
    }
}

// ---------------- bucket scan ----------------

__global__ __launch_bounds__(256) void bscan_kernel(const int* __restrict__ bcount,
                                                    int* __restrict__ bbase,
                                                    int* __restrict__ bcur,
                                                    int nbuck, int* __restrict__ offsets, int N) {
    __shared__ int sh[256];
    int base = threadIdx.x * 4;
    int v[4]; int tsum = 0;
#pragma unroll
    for (int i = 0; i < 4; ++i) { int idx = base + i; v[i] = (idx < nbuck) ? bcount[idx] : 0; tsum += v[i]; }
    sh[threadIdx.x] = tsum;
    __syncthreads();
#pragma unroll
    for (int off = 1; off < 256; off <<= 1) {
        int y = (threadIdx.x >= (unsigned)off) ? sh[threadIdx.x - off] : 0;
        __syncthreads();
        sh[threadIdx.x] += y;
        __syncthreads();
    }
    int ex = sh[threadIdx.x] - tsum;
#pragma unroll
    for (int i = 0; i < 4; ++i) {
        int idx = base + i;
        if (idx < nbuck) { bbase[idx] = ex; bcur[idx] = ex; ex += v[i]; }
        else if (idx == nbuck) { bbase[idx] = ex; offsets[N] = ex; }  // = E
    }
}

// ---------------- Phase A: block-local counting sort into buckets ----------------

__global__ __launch_bounds__(512) void binA_kernel(const int* __restrict__ rowv,
                                                   const int* __restrict__ colv,
                                                   int* __restrict__ bcur,
                                                   int* __restrict__ pairs,
                                                   int E, int nbuck) {
    __shared__ int hist[800];
    __shared__ int pos[800];
    int base = blockIdx.x * BINA_CHUNK;
    int end = min(base + BINA_CHUNK, E);
    for (int i = threadIdx.x; i < nbuck; i += 512) hist[i] = 0;
    __syncthreads();
    {
        int e = base + threadIdx.x * 4;
        for (; e + 4 <= end; e += 2048) {
            int4 c4 = *(const int4*)&colv[e];
            atomicAdd(&hist[c4.x >> 7], 1);
            atomicAdd(&hist[c4.y >> 7], 1);
            atomicAdd(&hist[c4.z >> 7], 1);
            atomicAdd(&hist[c4.w >> 7], 1);
        }
        for (; e < end; ++e) atomicAdd(&hist[colv[e] >> 7], 1);
    }
    __syncthreads();
    for (int b = threadIdx.x; b < nbuck; b += 512) {
        int c = hist[b];
        pos[b] = (c > 0) ? atomicAdd(&bcur[b], c) : 0;
    }
    __syncthreads();
    {
        int e = base + threadIdx.x * 4;
        for (; e + 4 <= end; e += 2048) {
            int4 c4 = *(const int4*)&colv[e];
            int4 r4 = *(const int4*)&rowv[e];
            int g0 = atomicAdd(&pos[c4.x >> 7], 1); pairs[g0] = (r4.x << 7) | (c4.x & 127);
            int g1 = atomicAdd(&pos[c4.y >> 7], 1); pairs[g1] = (r4.y << 7) | (c4.y & 127);
            int g2 = atomicAdd(&pos[c4.z >> 7], 1); pairs[g2] = (r4.z << 7) | (c4.z & 127);
            int g3 = atomicAdd(&pos[c4.w >> 7], 1); pairs[g3] = (r4.w << 7) | (c4.w & 127);
        }
        for (; e < end; ++e) {
            int c = colv[e];
            int g = atomicAdd(&pos[c >> 7], 1);
            pairs[g] = (rowv[e] << 7) | (c & 127);
        }
    }
}

// ---------------- Phase B: per bucket — node hist, scan, offsets+dinv, scatter ----------------

__global__ __launch_bounds__(512) void binB_kernel(const int* __restrict__ pairs,
                                                   const int* __restrict__ bbase,
                                                   int* __restrict__ offsets,
                                                   float* __restrict__ dinv,
                                                   int* __restrict__ edge_src, int N) {
    __shared__ int lcnt[128];
    __shared__ int sc[128];
    __shared__ int lcur[128];
    int nodeBeg = blockIdx.x << 7;
    int segBeg = bbase[blockIdx.x];
    int segEnd = bbase[blockIdx.x + 1];
    if (threadIdx.x < 128) lcnt[threadIdx.x] = 0;
    __syncthreads();
    for (int e = segBeg + threadIdx.x; e < segEnd; e += 512)
        atomicAdd(&lcnt[pairs[e] & 127], 1);
    __syncthreads();
    int v = (threadIdx.x < 128) ? lcnt[threadIdx.x] : 0;
    if (threadIdx.x < 128) sc[threadIdx.x] = v;
    __syncthreads();
    for (int off = 1; off < 128; off <<= 1) {
        int y = 0;
        if (threadIdx.x < 128 && threadIdx.x >= (unsigned)off) y = sc[threadIdx.x - off];
        __syncthreads();
        if (threadIdx.x < 128) sc[threadIdx.x] += y;
        __syncthreads();
    }
    if (threadIdx.x < 128) {
        int ex = sc[threadIdx.x] - v;
        lcur[threadIdx.x] = ex;
        int node = nodeBeg + threadIdx.x;
        if (node < N) {
            offsets[node] = segBeg + ex;
            dinv[node] = rsqrtf((float)(v + 1));
        }
    }
    __syncthreads();
    for (int e = segBeg + threadIdx.x; e < segEnd; e += 512) {
        int p = pairs[e];
        int rel = atomicAdd(&lcur[p & 127], 1);
        edge_src[segBeg + rel] = p >> 7;
    }
}

// ---------------- GEMM + dinv scale, fp16 out ----------------

template <int K, int NOUT>
__global__ __launch_bounds__(16 * (NOUT / 4)) void gemm_scale(const float* __restrict__ in_,
                                                              const float* __restrict__ W,
                                                              const float* __restrict__ dinv,
                                                              __half* __restrict__ out, int N) {
    constexpr int TPB = 16 * (NOUT / 4);
    constexpr int XPITCH = K + 4;
    __shared__ float xs[64 * XPITCH];
    __shared__ float ws[K * NOUT];

    const int tid = threadIdx.x;
    const int nodeBase = blockIdx.x * 64;

    for (int i = tid; i < K * NOUT / 4; i += TPB)
        *(float4*)&ws[i * 4] = *(const float4*)&W[i * 4];
    for (int i = tid; i < 64 * K / 4; i += TPB) {
        int row = i / (K / 4), c = i % (K / 4);
        int src = nodeBase + row; if (src >= N) src = N - 1;
        *(float4*)&xs[row * XPITCH + c * 4] = *(const float4*)&in_[(size_t)src * K + c * 4];
    }
    __syncthreads();

    const int jg = tid % (NOUT / 4);
    const int ng = tid / (NOUT / 4);

    float acc[4][4];
#pragma unroll
    for (int i = 0; i < 4; ++i)
#pragma unroll
        for (int j = 0; j < 4; ++j) acc[i][j] = 0.f;

    for (int kc = 0; kc < K / 4; ++kc) {
        float4 xv[4], wv[4];
#pragma unroll
        for (int ni = 0; ni < 4; ++ni)
            xv[ni] = *(const float4*)&xs[(ng * 4 + ni) * XPITCH + kc * 4];
#pragma unroll
        for (int t = 0; t < 4; ++t)
            wv[t] = *(const float4*)&ws[(kc * 4 + t) * NOUT + jg * 4];
#pragma unroll
        for (int ni = 0; ni < 4; ++ni) {
            acc[ni][0] = fmaf(xv[ni].x, wv[0].x, acc[ni][0]);
            acc[ni][1] = fmaf(xv[ni].x, wv[0].y, acc[ni][1]);
            acc[ni][2] = fmaf(xv[ni].x, wv[0].z, acc[ni][2]);
            acc[ni][3] = fmaf(xv[ni].x, wv[0].w, acc[ni][3]);
            acc[ni][0] = fmaf(xv[ni].y, wv[1].x, acc[ni][0]);
            acc[ni][1] = fmaf(xv[ni].y, wv[1].y, acc[ni][1]);
            acc[ni][2] = fmaf(xv[ni].y, wv[1].z, acc[ni][2]);
            acc[ni][3] = fmaf(xv[ni].y, wv[1].w, acc[ni][3]);
            acc[ni][0] = fmaf(xv[ni].z, wv[2].x, acc[ni][0]);
            acc[ni][1] = fmaf(xv[ni].z, wv[2].y, acc[ni][1]);
            acc[ni][2] = fmaf(xv[ni].z, wv[2].z, acc[ni][2]);
            acc[ni][3] = fmaf(xv[ni].z, wv[2].w, acc[ni][3]);
            acc[ni][0] = fmaf(xv[ni].w, wv[3].x, acc[ni][0]);
            acc[ni][1] = fmaf(xv[ni].w, wv[3].y, acc[ni][1]);
            acc[ni][2] = fmaf(xv[ni].w, wv[3].z, acc[ni][2]);
            acc[ni][3] = fmaf(xv[ni].w, wv[3].w, acc[ni][3]);
        }
    }

#pragma unroll
    for (int ni = 0; ni < 4; ++ni) {
        int node = nodeBase + ng * 4 + ni;
        if (node < N) {
            float dn = dinv[node];
            __half2* op = (__half2*)(out + (size_t)node * NOUT + jg * 4);
            op[0] = __floats2half2_rn(acc[ni][0] * dn, acc[ni][1] * dn);
            op[1] = __floats2half2_rn(acc[ni][2] * dn, acc[ni][3] * dn);
        }
    }
}

// ---------------- Pull aggregation: packed half2 gathers, fp32 accumulate ----------------

template <int F, bool RELU>
__global__ __launch_bounds__(256) void agg_pull(const __half* __restrict__ h,
                                                const float* __restrict__ dinv,
                                                const float* __restrict__ bias,
                                                const int* __restrict__ edge_src,
                                                const int* __restrict__ offsets,
                                                float* __restrict__ out, int N) {
    constexpr int LPN = F / 2;        // lanes per node
    constexpr int GPW = 64 / LPN;     // nodes per wave
    int lane = threadIdx.x & 63;
    int wave = (blockIdx.x * 256 + (int)threadIdx.x) >> 6;
    int g = lane / LPN;
    int fl = lane % LPN;              // feature-pair index
    int node = wave * GPW + g;
    if (node >= N) return;
    float dn = dinv[node];
    int beg = offsets[node], end = offsets[node + 1];
    const __half2* __restrict__ hp = (const __half2*)h;

    float2 sv = __half22float2(hp[(size_t)node * LPN + fl]);  // self-loop
    float a0x = sv.x, a0y = sv.y;
    float a1x = 0.f, a1y = 0.f, a2x = 0.f, a2y = 0.f, a3x = 0.f, a3y = 0.f;

    int j = beg;
    for (; j + 8 <= end; j += 8) {
        int s0 = edge_src[j],     s1 = edge_src[j + 1], s2 = edge_src[j + 2], s3 = edge_src[j + 3];
        int s4 = edge_src[j + 4], s5 = edge_src[j + 5], s6 = edge_src[j + 6], s7 = edge_src[j + 7];
        __half2 v0 = hp[(size_t)s0 * LPN + fl];
        __half2 v1 = hp[(size_t)s1 * LPN + fl];
        __half2 v2 = hp[(size_t)s2 * LPN + fl];
        __half2 v3 = hp[(size_t)s3 * LPN + fl];
        __half2 v4 = hp[(size_t)s4 * LPN + fl];
        __half2 v5 = hp[(size_t)s5 * LPN + fl];
        __half2 v6 = hp[(size_t)s6 * LPN + fl];
        __half2 v7 = hp[(size_t)s7 * LPN + fl];
        float2 f0 = __half22float2(v0), f1 = __half22float2(v1);
        float2 f2 = __half22float2(v2), f3 = __half22float2(v3);
        float2 f4 = __half22float2(v4), f5 = __half22float2(v5);
        float2 f6 = __half22float2(v6), f7 = __half22float2(v7);
        a0x += f0.x; a0y += f0.y; a1x += f1.x; a1y += f1.y;
        a2x += f2.x; a2y += f2.y; a3x += f3.x; a3y += f3.y;
        a0x += f4.x; a0y += f4.y; a1x += f5.x; a1y += f5.y;
        a2x += f6.x; a2y += f6.y; a3x += f7.x; a3y += f7.y;
    }
    for (; j + 2 <= end; j += 2) {
        int s0 = edge_src[j], s1 = edge_src[j + 1];
        float2 f0 = __half22float2(hp[(size_t)s0 * LPN + fl]);
        float2 f1 = __half22float2(hp[(size_t)s1 * LPN + fl]);
        a0x += f0.x; a0y += f0.y; a1x += f1.x; a1y += f1.y;
    }
    if (j < end) {
        float2 f0 = __half22float2(hp[(size_t)edge_src[j] * LPN + fl]);
        a0x += f0.x; a0y += f0.y;
    }

    float2 bv = *(const float2*)&bias[fl * 2];
    float rx = ((a0x + a1x) + (a2x + a3x)) * dn + bv.x;
    float ry = ((a0y + a1y) + (a2y + a3y)) * dn + bv.y;
    if (RELU) { rx = fmaxf(rx, 0.f); ry = fmaxf(ry, 0.f); }
    *(float2*)&out[(size_t)node * F + fl * 2] = make_float2(rx, ry);
}

// ---------------- Decode stage 1: uv[n] = [z@W1_top | z@W1_bot] (fp16 out) ----------------

__global__ __launch_bounds__(256) void gemm_uv(const float* __restrict__ z,   // [N,32]
                                               const float* __restrict__ W1,  // [64,64]
                                               __half* __restrict__ uv, int N) {
    constexpr int ZPITCH = 36;
    __shared__ float zs[64 * ZPITCH];
    __shared__ float ws[64 * 64];
    const int tid = threadIdx.x;
    const int nodeBase = blockIdx.x * 64;

    for (int i = tid; i < 64 * 64 / 4; i += 256)
        *(float4*)&ws[i * 4] = *(const float4*)&W1[i * 4];
    for (int i = tid; i < 64 * 8; i += 256) {
        int row = i / 8, c = i % 8;
        int src = nodeBase + row; if (src >= N) src = N - 1;
        *(float4*)&zs[row * ZPITCH + c * 4] = *(const float4*)&z[(size_t)src * 32 + c * 4];
    }
    __syncthreads();

    const int jg = tid % 16;
    const int ng = tid / 16;

    float au[4][4], av[4][4];
#pragma unroll
    for (int i = 0; i < 4; ++i)
#pragma unroll
        for (int j = 0; j < 4; ++j) { au[i][j] = 0.f; av[i][j] = 0.f; }

    for (int kc = 0; kc < 8; ++kc) {            // K = 32
        float4 xv[4], wu[4], wv2[4];
#pragma unroll
        for (int ni = 0; ni < 4; ++ni)
            xv[ni] = *(const float4*)&zs[(ng * 4 + ni) * ZPITCH + kc * 4];
#pragma unroll
        for (int t = 0; t < 4; ++t) {
            wu[t]  = *(const float4*)&ws[(kc * 4 + t) * 64 + jg * 4];
            wv2[t] = *(const float4*)&ws[(32 + kc * 4 + t) * 64 + jg * 4];
        }
#pragma unroll
        for (int ni = 0; ni < 4; ++ni) {
            float xk[4] = {xv[ni].x, xv[ni].y, xv[ni].z, xv[ni].w};
#pragma unroll
            for (int t = 0; t < 4; ++t) {
                au[ni][0] = fmaf(xk[t], wu[t].x, au[ni][0]);
                au[ni][1] = fmaf(xk[t], wu[t].y, au[ni][1]);
                au[ni][2] = fmaf(xk[t], wu[t].z, au[ni][2]);
                au[ni][3] = fmaf(xk[t], wu[t].w, au[ni][3]);
                av[ni][0] = fmaf(xk[t], wv2[t].x, av[ni][0]);
                av[ni][1] = fmaf(xk[t], wv2[t].y, av[ni][1]);
                av[ni][2] = fmaf(xk[t], wv2[t].z, av[ni][2]);
                av[ni][3] = fmaf(xk[t], wv2[t].w, av[ni][3]);
            }
        }
    }

#pragma unroll
    for (int ni = 0; ni < 4; ++ni) {
        int node = nodeBase + ng * 4 + ni;
        if (node < N) {
            __half2* pu = (__half2*)(uv + (size_t)node * 128 + jg * 4);
            pu[0] = __floats2half2_rn(au[ni][0], au[ni][1]);
            pu[1] = __floats2half2_rn(au[ni][2], au[ni][3]);
            __half2* pv = (__half2*)(uv + (size_t)node * 128 + 64 + jg * 4);
            pv[0] = __floats2half2_rn(av[ni][0], av[ni][1]);
            pv[1] = __floats2half2_rn(av[ni][2], av[ni][3]);
        }
    }
}

// ---------------- Decode stage 2: link_pred[e] = relu(u[a]+v[b]+b1)·w2 + b2 ----------------

__global__ __launch_bounds__(256) void decode_edge(const __half* __restrict__ uv,
                                                   const int* __restrict__ eli, int EL,
                                                   const float* __restrict__ lpb1,
                                                   const float* __restrict__ lpW2,
                                                   const float* __restrict__ lpb2,
                                                   float* __restrict__ out) {
    const int sub = threadIdx.x & 15;
    float4 b1r = *(const float4*)&lpb1[sub * 4];
    float4 w2r = *(const float4*)&lpW2[sub * 4];
    const float b2v = lpb2[0];
    int e = blockIdx.x * 16 + (threadIdx.x >> 4);
    if (e >= EL) return;
    int a = eli[e], b = eli[EL + e];
    const __half2* pa = (const __half2*)(uv + (size_t)a * 128 + sub * 4);
    const __half2* pb = (const __half2*)(uv + (size_t)b * 128 + 64 + sub * 4);
    float2 a01 = __half22float2(pa[0]), a23 = __half22float2(pa[1]);
    float2 b01 = __half22float2(pb[0]), b23 = __half22float2(pb[1]);
    float p = fmaxf(a01.x + b01.x + b1r.x, 0.f) * w2r.x;
    p = fmaf(fmaxf(a01.y + b01.y + b1r.y, 0.f), w2r.y, p);
    p = fmaf(fmaxf(a23.x + b23.x + b1r.z, 0.f), w2r.z, p);
    p = fmaf(fmaxf(a23.y + b23.y + b1r.w, 0.f), w2r.w, p);
    p += __shfl_down(p, 8, 16);
    p += __shfl_down(p, 4, 16);
    p += __shfl_down(p, 2, 16);
    p += __shfl_down(p, 1, 16);
    if (sub == 0) out[e] = p + b2v;
}

// ---------------- launch ----------------

extern "C" void kernel_launch(void* const* d_in, const int* in_sizes, int n_in,
                              void* d_out, int out_size, void* d_ws, size_t ws_size,
                              hipStream_t stream) {
    const float* x    = (const float*)d_in[0];
    const int* ei     = (const int*)d_in[1];
    const int* eli    = (const int*)d_in[2];
    const float* W1   = (const float*)d_in[3];
    const float* b1   = (const float*)d_in[4];
    const float* W2   = (const float*)d_in[5];
    const float* b2   = (const float*)d_in[6];
    const float* W3   = (const float*)d_in[7];
    const float* b3   = (const float*)d_in[8];
    const float* lpW1 = (const float*)d_in[9];
    const float* lpb1 = (const float*)d_in[10];
    const float* lpW2 = (const float*)d_in[11];
    const float* lpb2 = (const float*)d_in[12];

    const int N  = in_sizes[0] / 128;   // 100000
    const int E  = in_sizes[1] / 2;     // 3200000
    const int EL = in_sizes[2] / 2;     // 1000000

    char* p = (char*)d_ws;
    auto alloc = [&](size_t bytes) { void* r = (void*)p; p += (bytes + 255) & ~(size_t)255; return r; };
    float* dinv     = (float*)alloc((size_t)N * 4);
    int*   offsets  = (int*)alloc((size_t)(N + 1) * 4);
    int*   bcount   = (int*)alloc(1024 * 4);
    int*   bbase    = (int*)alloc(1024 * 4);
    int*   bcur     = (int*)alloc(1024 * 4);
    int*   edge_src = (int*)alloc((size_t)E * 4);
    __half* bufG    = (__half*)alloc((size_t)N * 64 * 2);   // fp16 messages h'
    float* bufZ     = (float*)alloc((size_t)N * 64 * 4);    // fp32 z1/z2
    __half* uvbuf   = (__half*)alloc((size_t)N * 128 * 2);  // fp16 uv
    int*   pairs    = (int*)uvbuf;  // alias: pairs (12.8MB) dead before gemm_uv writes uv

    const int* rowv = ei;        // edge_index[0] = source
    const int* colv = ei + E;    // edge_index[1] = target

    int nbuk = (N + 127) / 128;  // 782
    int nchunk = (E + BINA_CHUNK - 1) / BINA_CHUNK;

    hipMemsetAsync(bcount, 0, (size_t)nbuk * 4, stream);
    bhist_kernel<<<nchunk, 512, 0, stream>>>(colv, bcount, E, nbuk);
    bscan_kernel<<<1, 256, 0, stream>>>(bcount, bbase, bcur, nbuk, offsets, N);
    binA_kernel<<<nchunk, 512, 0, stream>>>(rowv, colv, bcur, pairs, E, nbuk);
    binB_kernel<<<nbuk, 512, 0, stream>>>(pairs, bbase, offsets, dinv, edge_src, N);

    float* zout = (float*)d_out + EL;   // z lives in the output tail (float32)

    int gblocks = (N + 63) / 64;  // 1563

    // agg_pull packed: GPW = 128/F nodes per wave; 4 waves per block.
    int aggblocks64 = (N + 7) / 8;     // F=64: 2 nodes/wave * 4 waves
    int aggblocks32 = (N + 15) / 16;   // F=32: 4 nodes/wave * 4 waves

    // layer 1: x[N,128] -> bufG h' (fp16) -> bufZ (fp32, relu)
    gemm_scale<128, 64><<<gblocks, 256, 0, stream>>>(x, W1, dinv, bufG, N);
    agg_pull<64, true><<<aggblocks64, 256, 0, stream>>>(bufG, dinv, b1, edge_src, offsets, bufZ, N);
    // layer 2
    gemm_scale<64, 64><<<gblocks, 256, 0, stream>>>(bufZ, W2, dinv, bufG, N);
    agg_pull<64, true><<<aggblocks64, 256, 0, stream>>>(bufG, dinv, b2, edge_src, offsets, bufZ, N);
    // layer 3: 32-wide, write z directly into d_out tail
    gemm_scale<64, 32><<<gblocks, 128, 0, stream>>>(bufZ, W3, dinv, bufG, N);
    agg_pull<32, false><<<aggblocks32, 256, 0, stream>>>(bufG, dinv, b3, edge_src, offsets, zout, N);
    // decode: per-node uv precompute (fp16), then per-edge gather+epilogue
    gemm_uv<<<gblocks, 256, 0, stream>>>(zout, lpW1, uvbuf, N);
    decode_edge<<<(EL + 15) / 16, 256, 0, stream>>>(uvbuf, eli, EL, lpb1, lpW2, lpb2, (float*)d_out);
}